// Round 1
// baseline (378.907 us; speedup 1.0000x reference)
//
#include <hip/hip_runtime.h>

#define NBATCH 8
#define SQL 512
#define SKL 512
#define DD 32
#define KF 1152            // padded feature dim (real 1121)
#define UT 528             // D*(D+1)/2
#define NOUT 1056          // 32 mean cols + 1024 cov cols

// ---------------------------------------------------------------------------
// Kernel 1: per-site inversion (register Gauss-Jordan, one wave per matrix)
// + feature construction.
// Lane c (0..63) holds augmented column c of [Cov | I] in registers; GJ via
// __shfl broadcasts of the pivot column — wave-lockstep, no barriers needed.
// ---------------------------------------------------------------------------
__global__ __launch_bounds__(64) void feat_kernel(
    const float* __restrict__ mean, const float* __restrict__ cov,
    float* __restrict__ feat, int qside)
{
    const int site = blockIdx.x;
    const float* covp = cov + (size_t)site * (DD * DD);
    const float* mup  = mean + (size_t)site * DD;
    float* fp = feat + (size_t)site * KF;
    const int lane = threadIdx.x;

    __shared__ float cov_s[DD][DD + 1];
    __shared__ float inv_s[DD][DD + 1];
    __shared__ float mu_s[DD];
    __shared__ float iv_s[DD];

    if (lane < DD) mu_s[lane] = mup[lane];

    float a[DD];
    if (lane < DD) {
        #pragma unroll
        for (int r = 0; r < DD; ++r) {
            float v = covp[r * DD + lane];
            a[r] = v;
            cov_s[r][lane] = v;
        }
    } else {
        const int c = lane - DD;
        #pragma unroll
        for (int r = 0; r < DD; ++r) a[r] = (r == c) ? 1.0f : 0.0f;
    }

    // Gauss-Jordan, no pivoting (SPD, cond ~2). Fully unrolled so a[] stays
    // in VGPRs (dynamic a[p] indexing forbids rolled loop).
    #pragma unroll
    for (int p = 0; p < DD; ++p) {
        float piv = __shfl(a[p], p);
        float rinv = 1.0f / piv;
        float fr[DD];
        #pragma unroll
        for (int r = 0; r < DD; ++r) fr[r] = __shfl(a[r], p);
        float t = rinv * a[p];          // scaled pivot-row element (lane-local)
        #pragma unroll
        for (int r = 0; r < DD; ++r)
            if (r != p) a[r] -= fr[r] * t;
        a[p] *= rinv;
    }

    if (lane >= DD) {
        const int c = lane - DD;
        #pragma unroll
        for (int r = 0; r < DD; ++r) inv_s[r][c] = a[r];
    }
    __syncthreads();

    if (lane < DD) {
        float s = 0.f;
        #pragma unroll
        for (int e = 0; e < DD; ++e) s += inv_s[lane][e] * mu_s[e];
        iv_s[lane] = s;                 // inv * mu
    }
    __syncthreads();

    float bias = 0.f;                   // mu^T inv mu
    #pragma unroll
    for (int d2 = 0; d2 < DD; ++d2) bias += mu_s[d2] * iv_s[d2];

    // Packed upper-triangle features.
    // q-side: [2w*(cov+mumu^T) | 2w*inv | -2*inv*mu | mu | 1 | 0pad]
    // k-side: [inv | cov+mumu^T | mu | -2*inv*mu | mu^T inv mu | 0pad]
    for (int idx = lane; idx < UT; idx += 64) {
        int d = 0, off = 0;
        while (off + (DD - d) <= idx) { off += (DD - d); ++d; }
        int e = d + (idx - off);
        float Mv = cov_s[d][e] + mu_s[d] * mu_s[e];
        float Iv = 0.5f * (inv_s[d][e] + inv_s[e][d]);
        float w = (d == e) ? 1.0f : 2.0f;
        if (qside) { fp[idx] = w * Mv; fp[UT + idx] = w * Iv; }
        else       { fp[idx] = Iv;     fp[UT + idx] = Mv; }
    }
    if (lane < DD) {
        float ivv = iv_s[lane], muv = mu_s[lane];
        if (qside) { fp[2*UT + lane] = -2.f * ivv; fp[2*UT + DD + lane] = muv; }
        else       { fp[2*UT + lane] = muv;        fp[2*UT + DD + lane] = -2.f * ivv; }
    }
    if (lane == 32) fp[2*UT + 2*DD] = qside ? 1.0f : bias;
    for (int i = 2*UT + 2*DD + 1 + lane; i < KF; i += 64) fp[i] = 0.0f;
}

// ---------------------------------------------------------------------------
// Kernel 2: score GEMM  P[b,q,k] = 0.25 * featq[b,q,:] . featk[b,k,:]
// 64x64 tile, BK=32, 256 threads, 4x4 microtile. fp32 VALU (no fp32 MFMA).
// ---------------------------------------------------------------------------
__global__ __launch_bounds__(256) void score_gemm(
    const float* __restrict__ fq, const float* __restrict__ fk,
    float* __restrict__ P)
{
    const int b = blockIdx.z, mt = blockIdx.y, nt = blockIdx.x;
    const float* A  = fq + (size_t)(b * SQL + mt * 64) * KF;
    const float* Bp = fk + (size_t)(b * SKL + nt * 64) * KF;
    float* C = P + (size_t)(b * SQL + mt * 64) * SKL + nt * 64;

    __shared__ __align__(16) float As[32][68];   // [k][m], pad 68 dodges conflicts
    __shared__ __align__(16) float Bs[32][68];   // [k][n]

    const int tid = threadIdx.x;
    const int tx = tid & 15, ty = tid >> 4;
    float acc[4][4] = {};

    for (int k0 = 0; k0 < KF; k0 += 32) {
        #pragma unroll
        for (int i = 0; i < 2; ++i) {
            int li = tid + i * 256;               // 0..511
            int row = li >> 3;                    // 0..63 tile row
            int kc = (li & 7) << 2;               // 0..28
            float4 va = *(const float4*)(A  + (size_t)row * KF + (k0 + kc));
            float4 vb = *(const float4*)(Bp + (size_t)row * KF + (k0 + kc));
            As[kc+0][row] = va.x; As[kc+1][row] = va.y; As[kc+2][row] = va.z; As[kc+3][row] = va.w;
            Bs[kc+0][row] = vb.x; Bs[kc+1][row] = vb.y; Bs[kc+2][row] = vb.z; Bs[kc+3][row] = vb.w;
        }
        __syncthreads();
        #pragma unroll
        for (int kk = 0; kk < 32; ++kk) {
            float4 av = *(const float4*)&As[kk][ty << 2];
            float4 bv = *(const float4*)&Bs[kk][tx << 2];
            float am[4] = {av.x, av.y, av.z, av.w};
            float bn[4] = {bv.x, bv.y, bv.z, bv.w};
            #pragma unroll
            for (int i = 0; i < 4; ++i)
                #pragma unroll
                for (int j = 0; j < 4; ++j)
                    acc[i][j] = fmaf(am[i], bn[j], acc[i][j]);
        }
        __syncthreads();
    }
    #pragma unroll
    for (int i = 0; i < 4; ++i)
        #pragma unroll
        for (int j = 0; j < 4; ++j)
            C[(size_t)((ty << 2) + i) * SKL + (tx << 2) + j] = 0.25f * acc[i][j];
}

// ---------------------------------------------------------------------------
// Kernel 3: row softmax over 512-wide rows (one block per (b,q))
// ---------------------------------------------------------------------------
__global__ __launch_bounds__(256) void softmax_rows(float* __restrict__ P)
{
    float* p = P + (size_t)blockIdx.x * SKL;
    const int tid = threadIdx.x;
    float2 v = *(float2*)(p + 2 * tid);
    float m = fmaxf(v.x, v.y);
    #pragma unroll
    for (int o = 32; o > 0; o >>= 1) m = fmaxf(m, __shfl_xor(m, o));
    __shared__ float redm[4], reds[4];
    const int wid = tid >> 6, ln = tid & 63;
    if (ln == 0) redm[wid] = m;
    __syncthreads();
    m = fmaxf(fmaxf(redm[0], redm[1]), fmaxf(redm[2], redm[3]));
    float e0 = __expf(v.x - m), e1 = __expf(v.y - m);
    float s = e0 + e1;
    #pragma unroll
    for (int o = 32; o > 0; o >>= 1) s += __shfl_xor(s, o);
    if (ln == 0) reds[wid] = s;
    __syncthreads();
    s = reds[0] + reds[1] + reds[2] + reds[3];
    float rs = 1.0f / s;
    *(float2*)(p + 2 * tid) = make_float2(e0 * rs, e1 * rs);
}

// ---------------------------------------------------------------------------
// Kernel 4: output GEMM  [out_mean | out_cov] = P . [v_mean | v_cov]
// N = 1056 virtual columns (17 tiles of 64, guarded).
// ---------------------------------------------------------------------------
__global__ __launch_bounds__(256) void out_gemm(
    const float* __restrict__ P, const float* __restrict__ vmean,
    const float* __restrict__ vcov, float* __restrict__ om, float* __restrict__ oc)
{
    const int b = blockIdx.z, mt = blockIdx.y, nt = blockIdx.x;
    const float* A = P + (size_t)(b * SQL + mt * 64) * SKL;
    const int n0 = nt * 64;

    __shared__ __align__(16) float As[32][68];   // [k][m]
    __shared__ __align__(16) float Bs[32][68];   // [k][n]

    const int tid = threadIdx.x;
    const int tx = tid & 15, ty = tid >> 4;
    float acc[4][4] = {};

    for (int k0 = 0; k0 < SKL; k0 += 32) {
        #pragma unroll
        for (int i = 0; i < 2; ++i) {
            int li = tid + i * 256;
            {   // A tile 64 rows x 32 k, transposed store
                int row = li >> 3;
                int kc = (li & 7) << 2;
                float4 va = *(const float4*)(A + (size_t)row * SKL + (k0 + kc));
                As[kc+0][row] = va.x; As[kc+1][row] = va.y; As[kc+2][row] = va.z; As[kc+3][row] = va.w;
            }
            {   // B tile 32 k-rows x 64 n-cols, virtual concat [v_mean | v_cov]
                int krow = li >> 4;
                int ng = (li & 15) << 2;
                int n = n0 + ng;
                int k = k0 + krow;
                float4 vb;
                if (n < 32)        vb = *(const float4*)(vmean + (size_t)(b * SKL + k) * DD + n);
                else if (n < NOUT) vb = *(const float4*)(vcov  + (size_t)(b * SKL + k) * (DD*DD) + (n - 32));
                else               vb = make_float4(0.f, 0.f, 0.f, 0.f);
                *(float4*)&Bs[krow][ng] = vb;
            }
        }
        __syncthreads();
        #pragma unroll
        for (int kk = 0; kk < 32; ++kk) {
            float4 av = *(const float4*)&As[kk][ty << 2];
            float4 bv = *(const float4*)&Bs[kk][tx << 2];
            float am[4] = {av.x, av.y, av.z, av.w};
            float bn[4] = {bv.x, bv.y, bv.z, bv.w};
            #pragma unroll
            for (int i = 0; i < 4; ++i)
                #pragma unroll
                for (int j = 0; j < 4; ++j)
                    acc[i][j] = fmaf(am[i], bn[j], acc[i][j]);
        }
        __syncthreads();
    }
    #pragma unroll
    for (int i = 0; i < 4; ++i) {
        int m = (mt << 6) + (ty << 2) + i;
        #pragma unroll
        for (int j = 0; j < 4; ++j) {
            int n = n0 + (tx << 2) + j;
            float v = acc[i][j];
            if (n < 32)        om[(size_t)(b * SQL + m) * DD + n] = v;
            else if (n < NOUT) oc[(size_t)(b * SQL + m) * (DD*DD) + (n - 32)] = v;
        }
    }
}

// ---------------------------------------------------------------------------
extern "C" void kernel_launch(void* const* d_in, const int* in_sizes, int n_in,
                              void* d_out, int out_size, void* d_ws, size_t ws_size,
                              hipStream_t stream)
{
    const float* q_mean = (const float*)d_in[0];
    const float* q_cov  = (const float*)d_in[1];
    const float* k_mean = (const float*)d_in[2];
    const float* k_cov  = (const float*)d_in[3];
    const float* v_mean = (const float*)d_in[4];
    const float* v_cov  = (const float*)d_in[5];

    float* out_mean = (float*)d_out;                       // [8,512,32]
    float* out_cov  = out_mean + (size_t)NBATCH * SQL * DD; // [8,512,32,32]

    // workspace layout (46.2 MB total)
    float* fq = (float*)d_ws;                              // 8*512*1152
    float* fk = fq + (size_t)NBATCH * SQL * KF;            // 8*512*1152
    float* P  = fk + (size_t)NBATCH * SKL * KF;            // 8*512*512

    feat_kernel<<<NBATCH * SQL, 64, 0, stream>>>(q_mean, q_cov, fq, 1);
    feat_kernel<<<NBATCH * SKL, 64, 0, stream>>>(k_mean, k_cov, fk, 0);
    score_gemm<<<dim3(SKL/64, SQL/64, NBATCH), 256, 0, stream>>>(fq, fk, P);
    softmax_rows<<<NBATCH * SQL, 256, 0, stream>>>(P);
    out_gemm<<<dim3(17, SQL/64, NBATCH), 256, 0, stream>>>(P, v_mean, v_cov, out_mean, out_cov);
}

// Round 2
// 306.570 us; speedup vs baseline: 1.2360x; 1.2360x over previous
//
#include <hip/hip_runtime.h>

#define NBATCH 8
#define SQL 512
#define SKL 512
#define DD 32
#define KF 1152            // padded feature dim (real 1121)
#define UT 528             // D*(D+1)/2
#define NOUT 1056          // 32 mean cols + 1024 cov cols
#define NVT 1088           // Vt rows padded to 17*64
#define LDA 40             // LDS row stride (elems) for 32-elem K rows: 80B, 16B-aligned, 2-way-conflict only

typedef short short8 __attribute__((ext_vector_type(8)));   // 8 bf16 bit-patterns (4 VGPRs)
typedef float f32x4 __attribute__((ext_vector_type(4)));
typedef unsigned short ushort_t;

__device__ __forceinline__ ushort_t f2bf(float f) {          // fp32 -> bf16 bits, RNE
    unsigned int u = __float_as_uint(f);
    return (ushort_t)((u + 0x7fffu + ((u >> 16) & 1u)) >> 16);
}
__device__ __forceinline__ float bf2f(ushort_t h) {
    return __uint_as_float(((unsigned int)h) << 16);
}
__device__ __forceinline__ void wsplit(ushort_t* __restrict__ h, ushort_t* __restrict__ l,
                                       size_t idx, float v) {
    ushort_t hb = f2bf(v);
    h[idx] = hb;
    l[idx] = f2bf(v - bf2f(hb));
}

// ---------------------------------------------------------------------------
// Kernel 1: per-site inversion (register Gauss-Jordan, one wave per matrix)
// + packed symmetric features, emitted as bf16 hi/lo split.
// ---------------------------------------------------------------------------
__global__ __launch_bounds__(64) void feat_kernel(
    const float* __restrict__ mean, const float* __restrict__ cov,
    ushort_t* __restrict__ fh, ushort_t* __restrict__ fl, int qside)
{
    const int site = blockIdx.x;
    const float* covp = cov + (size_t)site * (DD * DD);
    const float* mup  = mean + (size_t)site * DD;
    const size_t fo = (size_t)site * KF;
    const int lane = threadIdx.x;

    __shared__ float cov_s[DD][DD + 1];
    __shared__ float inv_s[DD][DD + 1];
    __shared__ float mu_s[DD];
    __shared__ float iv_s[DD];

    if (lane < DD) mu_s[lane] = mup[lane];

    float a[DD];
    if (lane < DD) {
        #pragma unroll
        for (int r = 0; r < DD; ++r) {
            float v = covp[r * DD + lane];
            a[r] = v;
            cov_s[r][lane] = v;
        }
    } else {
        const int c = lane - DD;
        #pragma unroll
        for (int r = 0; r < DD; ++r) a[r] = (r == c) ? 1.0f : 0.0f;
    }

    // Gauss-Jordan, no pivoting (SPD, cond ~2), wave-lockstep via shuffles.
    #pragma unroll
    for (int p = 0; p < DD; ++p) {
        float piv = __shfl(a[p], p);
        float rinv = 1.0f / piv;
        float fr[DD];
        #pragma unroll
        for (int r = 0; r < DD; ++r) fr[r] = __shfl(a[r], p);
        float t = rinv * a[p];
        #pragma unroll
        for (int r = 0; r < DD; ++r)
            if (r != p) a[r] -= fr[r] * t;
        a[p] *= rinv;
    }

    if (lane >= DD) {
        const int c = lane - DD;
        #pragma unroll
        for (int r = 0; r < DD; ++r) inv_s[r][c] = a[r];
    }
    __syncthreads();

    if (lane < DD) {
        float s = 0.f;
        #pragma unroll
        for (int e = 0; e < DD; ++e) s += inv_s[lane][e] * mu_s[e];
        iv_s[lane] = s;                 // inv * mu
    }
    __syncthreads();

    float bias = 0.f;                   // mu^T inv mu
    #pragma unroll
    for (int d2 = 0; d2 < DD; ++d2) bias += mu_s[d2] * iv_s[d2];

    for (int idx = lane; idx < UT; idx += 64) {
        int d = 0, off = 0;
        while (off + (DD - d) <= idx) { off += (DD - d); ++d; }
        int e = d + (idx - off);
        float Mv = cov_s[d][e] + mu_s[d] * mu_s[e];
        float Iv = 0.5f * (inv_s[d][e] + inv_s[e][d]);
        float w = (d == e) ? 1.0f : 2.0f;
        if (qside) { wsplit(fh, fl, fo + idx, w * Mv); wsplit(fh, fl, fo + UT + idx, w * Iv); }
        else       { wsplit(fh, fl, fo + idx, Iv);     wsplit(fh, fl, fo + UT + idx, Mv); }
    }
    if (lane < DD) {
        float ivv = iv_s[lane], muv = mu_s[lane];
        if (qside) { wsplit(fh, fl, fo + 2*UT + lane, -2.f * ivv); wsplit(fh, fl, fo + 2*UT + DD + lane, muv); }
        else       { wsplit(fh, fl, fo + 2*UT + lane, muv);        wsplit(fh, fl, fo + 2*UT + DD + lane, -2.f * ivv); }
    }
    if (lane == 32) wsplit(fh, fl, fo + 2*UT + 2*DD, qside ? 1.0f : bias);
    for (int i = 2*UT + 2*DD + 1 + lane; i < KF; i += 64) { fh[fo + i] = 0; fl[fo + i] = 0; }
}

// ---------------------------------------------------------------------------
// Split-bf16 MFMA GEMM: C = A . B^T_rowmajor with A,B stored K-contiguous,
// 3-product split (Ah*Bh + Ah*Bl + Al*Bh). Tile 128(M) x 64(N), BK=32,
// 256 threads = 4 waves in 2x2, each wave 64x32 via 4x2 mfma_f32_16x16x32_bf16.
// MODE 0: score  (KSTRIDE=KF,  C0 = js fp32, scale 0.25)
// MODE 1: output (KSTRIDE=512, C0 = out_mean, C1 = out_cov, col routing)
// ---------------------------------------------------------------------------
template<int KSTRIDE, int KITERS, int MODE>
__global__ __launch_bounds__(256) void gemm_split(
    const ushort_t* __restrict__ Ah_g, const ushort_t* __restrict__ Al_g,
    const ushort_t* __restrict__ Bh_g, const ushort_t* __restrict__ Bl_g,
    float* __restrict__ C0, float* __restrict__ C1)
{
    const int b = blockIdx.z, mt = blockIdx.y, nt = blockIdx.x;
    const int tid = threadIdx.x, lane = tid & 63, wid = tid >> 6;
    const int wm = wid & 1, wn = wid >> 1;
    const int BROWS = MODE ? NVT : SKL;

    const ushort_t* Ah = Ah_g + ((size_t)b * SQL + mt * 128) * KSTRIDE;
    const ushort_t* Al = Al_g + ((size_t)b * SQL + mt * 128) * KSTRIDE;
    const ushort_t* Bh = Bh_g + ((size_t)b * BROWS + nt * 64) * KSTRIDE;
    const ushort_t* Bl = Bl_g + ((size_t)b * BROWS + nt * 64) * KSTRIDE;

    __shared__ __align__(16) ushort_t AsH[128 * LDA];
    __shared__ __align__(16) ushort_t AsL[128 * LDA];
    __shared__ __align__(16) ushort_t BsH[64 * LDA];
    __shared__ __align__(16) ushort_t BsL[64 * LDA];

    const int srow = tid >> 2;            // 0..63
    const int kp   = (tid & 3) * 8;       // elem offset within 32-elem K row

    const int fm = lane & 15;             // frag row (A) / col (B)
    const int q8 = (lane >> 4) * 8;       // frag K offset

    f32x4 acc[4][2];
    #pragma unroll
    for (int i = 0; i < 4; ++i)
        #pragma unroll
        for (int j = 0; j < 2; ++j)
            acc[i][j] = (f32x4){0.f, 0.f, 0.f, 0.f};

    for (int it = 0; it < KITERS; ++it) {
        const int k0 = it * 32;
        const uint4 a0 = *(const uint4*)(Ah + (size_t)srow        * KSTRIDE + k0 + kp);
        const uint4 a1 = *(const uint4*)(Ah + (size_t)(srow + 64) * KSTRIDE + k0 + kp);
        const uint4 a2 = *(const uint4*)(Al + (size_t)srow        * KSTRIDE + k0 + kp);
        const uint4 a3 = *(const uint4*)(Al + (size_t)(srow + 64) * KSTRIDE + k0 + kp);
        const uint4 b0 = *(const uint4*)(Bh + (size_t)srow        * KSTRIDE + k0 + kp);
        const uint4 b1 = *(const uint4*)(Bl + (size_t)srow        * KSTRIDE + k0 + kp);

        __syncthreads();                  // prior iter's frag reads complete
        *(uint4*)&AsH[srow        * LDA + kp] = a0;
        *(uint4*)&AsH[(srow + 64) * LDA + kp] = a1;
        *(uint4*)&AsL[srow        * LDA + kp] = a2;
        *(uint4*)&AsL[(srow + 64) * LDA + kp] = a3;
        *(uint4*)&BsH[srow        * LDA + kp] = b0;
        *(uint4*)&BsL[srow        * LDA + kp] = b1;
        __syncthreads();

        short8 ah[4], al[4], bh[2], bl[2];
        #pragma unroll
        for (int i = 0; i < 4; ++i) {
            const int r = wm * 64 + i * 16 + fm;
            ah[i] = *(const short8*)&AsH[r * LDA + q8];
            al[i] = *(const short8*)&AsL[r * LDA + q8];
        }
        #pragma unroll
        for (int j = 0; j < 2; ++j) {
            const int r = wn * 32 + j * 16 + fm;
            bh[j] = *(const short8*)&BsH[r * LDA + q8];
            bl[j] = *(const short8*)&BsL[r * LDA + q8];
        }
        #pragma unroll
        for (int i = 0; i < 4; ++i)
            #pragma unroll
            for (int j = 0; j < 2; ++j) {
                acc[i][j] = __builtin_amdgcn_mfma_f32_16x16x32_bf16(ah[i], bh[j], acc[i][j], 0, 0, 0);
                acc[i][j] = __builtin_amdgcn_mfma_f32_16x16x32_bf16(ah[i], bl[j], acc[i][j], 0, 0, 0);
                acc[i][j] = __builtin_amdgcn_mfma_f32_16x16x32_bf16(al[i], bh[j], acc[i][j], 0, 0, 0);
            }
    }

    // Epilogue: C/D layout col=lane&15, row=(lane>>4)*4+reg (m89-verified)
    const int crow0 = (lane >> 4) * 4;
    const int ccol = lane & 15;
    #pragma unroll
    for (int i = 0; i < 4; ++i) {
        const int m = mt * 128 + wm * 64 + i * 16 + crow0;
        #pragma unroll
        for (int j = 0; j < 2; ++j) {
            const int n = nt * 64 + wn * 32 + j * 16 + ccol;
            #pragma unroll
            for (int r = 0; r < 4; ++r) {
                const float v = acc[i][j][r];
                const size_t rowb = (size_t)b * SQL + (m + r);
                if (MODE == 0) {
                    C0[rowb * SKL + n] = 0.25f * v;
                } else {
                    if (n < DD)        C0[rowb * DD + n] = v;
                    else if (n < NOUT) C1[rowb * (DD * DD) + (n - DD)] = v;
                }
            }
        }
    }
}

// ---------------------------------------------------------------------------
// Kernel 3: row softmax over 512-wide rows -> bf16 hi/lo P
// ---------------------------------------------------------------------------
__global__ __launch_bounds__(256) void softmax_rows(
    const float* __restrict__ js, ushort_t* __restrict__ ph, ushort_t* __restrict__ pl)
{
    const float* p = js + (size_t)blockIdx.x * SKL;
    const int tid = threadIdx.x;
    float2 v = *(const float2*)(p + 2 * tid);
    float m = fmaxf(v.x, v.y);
    #pragma unroll
    for (int o = 32; o > 0; o >>= 1) m = fmaxf(m, __shfl_xor(m, o));
    __shared__ float redm[4], reds[4];
    const int wid = tid >> 6, ln = tid & 63;
    if (ln == 0) redm[wid] = m;
    __syncthreads();
    m = fmaxf(fmaxf(redm[0], redm[1]), fmaxf(redm[2], redm[3]));
    float e0 = __expf(v.x - m), e1 = __expf(v.y - m);
    float s = e0 + e1;
    #pragma unroll
    for (int o = 32; o > 0; o >>= 1) s += __shfl_xor(s, o);
    if (ln == 0) reds[wid] = s;
    __syncthreads();
    s = reds[0] + reds[1] + reds[2] + reds[3];
    float rs = 1.0f / s;
    size_t o = (size_t)blockIdx.x * SKL + 2 * tid;
    wsplit(ph, pl, o,     e0 * rs);
    wsplit(ph, pl, o + 1, e1 * rs);
}

// ---------------------------------------------------------------------------
// Kernel 4: Vt = [v_mean | v_cov]^T per batch, bf16 hi/lo, [n][k] layout,
// zero-padded to NVT rows. LDS 32x32 tile transpose.
// ---------------------------------------------------------------------------
__global__ __launch_bounds__(256) void vsplit_kernel(
    const float* __restrict__ vmean, const float* __restrict__ vcov,
    ushort_t* __restrict__ vth, ushort_t* __restrict__ vtl)
{
    __shared__ float t[32][33];
    const int n0 = blockIdx.x * 32, k0 = blockIdx.y * 32, b = blockIdx.z;
    const int tx = threadIdx.x, ty = threadIdx.y;
    for (int r = ty; r < 32; r += 8) {              // r = k-offset; coalesced over tx=n
        const int k = k0 + r, n = n0 + tx;
        float v;
        if (n0 == 0)          v = vmean[((size_t)b * SKL + k) * DD + n];
        else if (n0 >= NOUT)  v = 0.f;
        else                  v = vcov[((size_t)b * SKL + k) * (DD * DD) + (n - DD)];
        t[tx][r] = v;
    }
    __syncthreads();
    for (int r = ty; r < 32; r += 8) {              // r = n-offset; coalesced over tx=k
        const int n = n0 + r, k = k0 + tx;
        const float v = t[r][tx];
        wsplit(vth, vtl, ((size_t)b * NVT + n) * SKL + k, v);
    }
}

// ---------------------------------------------------------------------------
extern "C" void kernel_launch(void* const* d_in, const int* in_sizes, int n_in,
                              void* d_out, int out_size, void* d_ws, size_t ws_size,
                              hipStream_t stream)
{
    const float* q_mean = (const float*)d_in[0];
    const float* q_cov  = (const float*)d_in[1];
    const float* k_mean = (const float*)d_in[2];
    const float* k_cov  = (const float*)d_in[3];
    const float* v_mean = (const float*)d_in[4];
    const float* v_cov  = (const float*)d_in[5];

    float* out_mean = (float*)d_out;                        // [8,512,32]
    float* out_cov  = out_mean + (size_t)NBATCH * SQL * DD; // [8,512,32,32]

    // workspace layout (46.1 MB, same footprint as round 0):
    //   fq_h/fq_l 9.44MB each | fk_h/fk_l 9.44MB each | js 8.39MB
    // After score_gemm the feature arrays are dead, so:
    //   vt_h aliases fq_h (8.91MB<=9.44), vt_l aliases fq_l
    //   p_h  aliases fk_h (4.19MB),       p_l  aliases fk_l
    char* w = (char*)d_ws;
    const size_t FQN = (size_t)NBATCH * SQL * KF;           // 4,718,592 elems
    ushort_t* fq_h = (ushort_t*)w;
    ushort_t* fq_l = fq_h + FQN;
    ushort_t* fk_h = fq_l + FQN;
    ushort_t* fk_l = fk_h + FQN;
    float*    js   = (float*)(fk_l + FQN);                  // 8*512*512 fp32
    ushort_t* vt_h = fq_h;
    ushort_t* vt_l = fq_l;
    ushort_t* p_h  = fk_h;
    ushort_t* p_l  = fk_l;

    feat_kernel<<<NBATCH * SQL, 64, 0, stream>>>(q_mean, q_cov, fq_h, fq_l, 1);
    feat_kernel<<<NBATCH * SKL, 64, 0, stream>>>(k_mean, k_cov, fk_h, fk_l, 0);
    gemm_split<KF, KF / 32, 0><<<dim3(SKL / 64, SQL / 128, NBATCH), 256, 0, stream>>>(
        fq_h, fq_l, fk_h, fk_l, js, nullptr);
    vsplit_kernel<<<dim3(NVT / 32, SKL / 32, NBATCH), dim3(32, 8), 0, stream>>>(
        v_mean, v_cov, vt_h, vt_l);
    softmax_rows<<<NBATCH * SQL, 256, 0, stream>>>(js, p_h, p_l);
    gemm_split<SKL, SKL / 32, 1><<<dim3(NVT / 64, SQL / 128, NBATCH), 256, 0, stream>>>(
        p_h, p_l, vt_h, vt_l, out_mean, out_cov);
}

// Round 3
// 227.929 us; speedup vs baseline: 1.6624x; 1.3450x over previous
//
#include <hip/hip_runtime.h>

#define NBATCH 8
#define SQL 512
#define SKL 512
#define DD 32
#define KF 1152            // padded feature dim (real 1121)
#define UT 528             // D*(D+1)/2
#define NOUT 1056          // 32 mean cols + 1024 cov cols
#define NVT 1088           // Vt rows padded to 17*64
#define LDA 40             // LDS row stride (elems): 80B, 16B-aligned, 2-way-conflict only

typedef short short8 __attribute__((ext_vector_type(8)));   // 8 bf16 bit-patterns (4 VGPRs)
typedef float f32x4 __attribute__((ext_vector_type(4)));
typedef unsigned short ushort_t;

__device__ __forceinline__ ushort_t f2bf(float f) {          // fp32 -> bf16 bits, RNE
    unsigned int u = __float_as_uint(f);
    return (ushort_t)((u + 0x7fffu + ((u >> 16) & 1u)) >> 16);
}
__device__ __forceinline__ float bf2f(ushort_t h) {
    return __uint_as_float(((unsigned int)h) << 16);
}
__device__ __forceinline__ void wsplit(ushort_t* __restrict__ h, ushort_t* __restrict__ l,
                                       size_t idx, float v) {
    ushort_t hb = f2bf(v);
    h[idx] = hb;
    l[idx] = f2bf(v - bf2f(hb));
}
__device__ __forceinline__ float rdlane(float x, int l) {    // wave-uniform broadcast -> SGPR
    return __int_as_float(__builtin_amdgcn_readlane(__float_as_int(x), l));
}

// ---------------------------------------------------------------------------
// Kernel 1 (merged q+k): per-site inversion, one wave per matrix.
// Lane c holds augmented column c of [Cov | I] in VGPRs; pivot-row broadcasts
// via v_readlane (constant lane index -> SGPR, no LDS, no fr[] VGPR array).
// Then packed symmetric features, emitted as bf16 hi/lo split.
// ---------------------------------------------------------------------------
__global__ __launch_bounds__(64) void feat_kernel(
    const float* __restrict__ qm, const float* __restrict__ qc,
    const float* __restrict__ km, const float* __restrict__ kc,
    ushort_t* __restrict__ fqh, ushort_t* __restrict__ fql,
    ushort_t* __restrict__ fkh, ushort_t* __restrict__ fkl)
{
    const int qside = (blockIdx.y == 0);
    const float* mean = qside ? qm : km;
    const float* cov  = qside ? qc : kc;
    ushort_t* fh = qside ? fqh : fkh;
    ushort_t* fl = qside ? fql : fkl;

    const int site = blockIdx.x;
    const float* covp = cov + (size_t)site * (DD * DD);
    const float* mup  = mean + (size_t)site * DD;
    const size_t fo = (size_t)site * KF;
    const int lane = threadIdx.x;

    __shared__ float cov_s[DD][DD + 1];
    __shared__ float inv_s[DD][DD + 1];
    __shared__ float mu_s[DD];
    __shared__ float iv_s[DD];

    if (lane < DD) mu_s[lane] = mup[lane];

    float a[DD];
    if (lane < DD) {
        #pragma unroll
        for (int r = 0; r < DD; ++r) {
            float v = covp[r * DD + lane];
            a[r] = v;
            cov_s[r][lane] = v;
        }
    } else {
        const int c = lane - DD;
        #pragma unroll
        for (int r = 0; r < DD; ++r) a[r] = (r == c) ? 1.0f : 0.0f;
    }

    // Gauss-Jordan, no pivoting (SPD, cond ~2). Pivot broadcasts are
    // wave-uniform readlanes (SGPR), so per-lane state is just a[32].
    #pragma unroll
    for (int p = 0; p < DD; ++p) {
        float piv = rdlane(a[p], p);
        float rinv = 1.0f / piv;
        float t = a[p] * rinv;            // scaled pivot row (lane-local elem)
        #pragma unroll
        for (int r = 0; r < DD; ++r) {
            if (r != p) {
                float fr = rdlane(a[r], p);   // SGPR, read before a[r] update
                a[r] = fmaf(-fr, t, a[r]);
            }
        }
        a[p] = t;
    }

    if (lane >= DD) {
        const int c = lane - DD;
        #pragma unroll
        for (int r = 0; r < DD; ++r) inv_s[r][c] = a[r];
    }
    __syncthreads();

    if (lane < DD) {
        float s = 0.f;
        #pragma unroll
        for (int e = 0; e < DD; ++e) s += inv_s[lane][e] * mu_s[e];
        iv_s[lane] = s;                 // inv * mu
    }
    __syncthreads();

    float bias = 0.f;                   // mu^T inv mu
    #pragma unroll
    for (int d2 = 0; d2 < DD; ++d2) bias += mu_s[d2] * iv_s[d2];

    // Packed upper-triangle features; closed-form (d,e) from flat idx:
    // off(d) = d*(65-d)/2, d = floor((65 - sqrt(4225 - 8 idx))/2) (+-1 fix)
    for (int idx = lane; idx < UT; idx += 64) {
        int d = (int)((65.0f - sqrtf(4225.0f - 8.0f * (float)idx)) * 0.5f);
        if (d > 0 && (d * (65 - d)) / 2 > idx) --d;
        if (((d + 1) * (64 - d)) / 2 <= idx) ++d;
        int off = (d * (65 - d)) / 2;
        int e = d + (idx - off);
        float Mv = cov_s[d][e] + mu_s[d] * mu_s[e];
        float Iv = 0.5f * (inv_s[d][e] + inv_s[e][d]);
        float w = (d == e) ? 1.0f : 2.0f;
        if (qside) { wsplit(fh, fl, fo + idx, w * Mv); wsplit(fh, fl, fo + UT + idx, w * Iv); }
        else       { wsplit(fh, fl, fo + idx, Iv);     wsplit(fh, fl, fo + UT + idx, Mv); }
    }
    if (lane < DD) {
        float ivv = iv_s[lane], muv = mu_s[lane];
        if (qside) { wsplit(fh, fl, fo + 2*UT + lane, -2.f * ivv); wsplit(fh, fl, fo + 2*UT + DD + lane, muv); }
        else       { wsplit(fh, fl, fo + 2*UT + lane, muv);        wsplit(fh, fl, fo + 2*UT + DD + lane, -2.f * ivv); }
    }
    if (lane == 32) wsplit(fh, fl, fo + 2*UT + 2*DD, qside ? 1.0f : bias);
    for (int i = 2*UT + 2*DD + 1 + lane; i < KF; i += 64) { fh[fo + i] = 0; fl[fo + i] = 0; }
}

// ---------------------------------------------------------------------------
// Split-bf16 MFMA GEMM: C = A . B^T_rowmajor with A,B stored K-contiguous,
// 3-product split (Ah*Bh + Ah*Bl + Al*Bh). Tile 128(M) x 64(N), BK=32,
// 256 threads = 4 waves in 2x2, each wave 64x32 via 4x2 mfma_f32_16x16x32_bf16.
// MODE 0: score  (KSTRIDE=KF,  C0 = js fp32, scale 0.25)
// MODE 1: output (KSTRIDE=512, C0 = out_mean, C1 = out_cov, col routing)
// ---------------------------------------------------------------------------
template<int KSTRIDE, int KITERS, int MODE>
__global__ __launch_bounds__(256) void gemm_split(
    const ushort_t* __restrict__ Ah_g, const ushort_t* __restrict__ Al_g,
    const ushort_t* __restrict__ Bh_g, const ushort_t* __restrict__ Bl_g,
    float* __restrict__ C0, float* __restrict__ C1)
{
    const int b = blockIdx.z, mt = blockIdx.y, nt = blockIdx.x;
    const int tid = threadIdx.x, lane = tid & 63, wid = tid >> 6;
    const int wm = wid & 1, wn = wid >> 1;
    const int BROWS = MODE ? NVT : SKL;

    const ushort_t* Ah = Ah_g + ((size_t)b * SQL + mt * 128) * KSTRIDE;
    const ushort_t* Al = Al_g + ((size_t)b * SQL + mt * 128) * KSTRIDE;
    const ushort_t* Bh = Bh_g + ((size_t)b * BROWS + nt * 64) * KSTRIDE;
    const ushort_t* Bl = Bl_g + ((size_t)b * BROWS + nt * 64) * KSTRIDE;

    __shared__ __align__(16) ushort_t AsH[128 * LDA];
    __shared__ __align__(16) ushort_t AsL[128 * LDA];
    __shared__ __align__(16) ushort_t BsH[64 * LDA];
    __shared__ __align__(16) ushort_t BsL[64 * LDA];

    const int srow = tid >> 2;            // 0..63
    const int kp   = (tid & 3) * 8;       // elem offset within 32-elem K row

    const int fm = lane & 15;             // frag row (A) / col (B)
    const int q8 = (lane >> 4) * 8;       // frag K offset

    f32x4 acc[4][2];
    #pragma unroll
    for (int i = 0; i < 4; ++i)
        #pragma unroll
        for (int j = 0; j < 2; ++j)
            acc[i][j] = (f32x4){0.f, 0.f, 0.f, 0.f};

    for (int it = 0; it < KITERS; ++it) {
        const int k0 = it * 32;
        const uint4 a0 = *(const uint4*)(Ah + (size_t)srow        * KSTRIDE + k0 + kp);
        const uint4 a1 = *(const uint4*)(Ah + (size_t)(srow + 64) * KSTRIDE + k0 + kp);
        const uint4 a2 = *(const uint4*)(Al + (size_t)srow        * KSTRIDE + k0 + kp);
        const uint4 a3 = *(const uint4*)(Al + (size_t)(srow + 64) * KSTRIDE + k0 + kp);
        const uint4 b0 = *(const uint4*)(Bh + (size_t)srow        * KSTRIDE + k0 + kp);
        const uint4 b1 = *(const uint4*)(Bl + (size_t)srow        * KSTRIDE + k0 + kp);

        __syncthreads();                  // prior iter's frag reads complete
        *(uint4*)&AsH[srow        * LDA + kp] = a0;
        *(uint4*)&AsH[(srow + 64) * LDA + kp] = a1;
        *(uint4*)&AsL[srow        * LDA + kp] = a2;
        *(uint4*)&AsL[(srow + 64) * LDA + kp] = a3;
        *(uint4*)&BsH[srow        * LDA + kp] = b0;
        *(uint4*)&BsL[srow        * LDA + kp] = b1;
        __syncthreads();

        short8 ah[4], al[4], bh[2], bl[2];
        #pragma unroll
        for (int i = 0; i < 4; ++i) {
            const int r = wm * 64 + i * 16 + fm;
            ah[i] = *(const short8*)&AsH[r * LDA + q8];
            al[i] = *(const short8*)&AsL[r * LDA + q8];
        }
        #pragma unroll
        for (int j = 0; j < 2; ++j) {
            const int r = wn * 32 + j * 16 + fm;
            bh[j] = *(const short8*)&BsH[r * LDA + q8];
            bl[j] = *(const short8*)&BsL[r * LDA + q8];
        }
        #pragma unroll
        for (int i = 0; i < 4; ++i)
            #pragma unroll
            for (int j = 0; j < 2; ++j) {
                acc[i][j] = __builtin_amdgcn_mfma_f32_16x16x32_bf16(ah[i], bh[j], acc[i][j], 0, 0, 0);
                acc[i][j] = __builtin_amdgcn_mfma_f32_16x16x32_bf16(ah[i], bl[j], acc[i][j], 0, 0, 0);
                acc[i][j] = __builtin_amdgcn_mfma_f32_16x16x32_bf16(al[i], bh[j], acc[i][j], 0, 0, 0);
            }
    }

    // Epilogue: C/D layout col=lane&15, row=(lane>>4)*4+reg (m89-verified)
    const int crow0 = (lane >> 4) * 4;
    const int ccol = lane & 15;
    #pragma unroll
    for (int i = 0; i < 4; ++i) {
        const int m = mt * 128 + wm * 64 + i * 16 + crow0;
        #pragma unroll
        for (int j = 0; j < 2; ++j) {
            const int n = nt * 64 + wn * 32 + j * 16 + ccol;
            #pragma unroll
            for (int r = 0; r < 4; ++r) {
                const float v = acc[i][j][r];
                const size_t rowb = (size_t)b * SQL + (m + r);
                if (MODE == 0) {
                    C0[rowb * SKL + n] = 0.25f * v;
                } else {
                    if (n < DD)        C0[rowb * DD + n] = v;
                    else if (n < NOUT) C1[rowb * (DD * DD) + (n - DD)] = v;
                }
            }
        }
    }
}

// ---------------------------------------------------------------------------
// Kernel 3: row softmax over 512-wide rows -> bf16 hi/lo P
// ---------------------------------------------------------------------------
__global__ __launch_bounds__(256) void softmax_rows(
    const float* __restrict__ js, ushort_t* __restrict__ ph, ushort_t* __restrict__ pl)
{
    const float* p = js + (size_t)blockIdx.x * SKL;
    const int tid = threadIdx.x;
    float2 v = *(const float2*)(p + 2 * tid);
    float m = fmaxf(v.x, v.y);
    #pragma unroll
    for (int o = 32; o > 0; o >>= 1) m = fmaxf(m, __shfl_xor(m, o));
    __shared__ float redm[4], reds[4];
    const int wid = tid >> 6, ln = tid & 63;
    if (ln == 0) redm[wid] = m;
    __syncthreads();
    m = fmaxf(fmaxf(redm[0], redm[1]), fmaxf(redm[2], redm[3]));
    float e0 = __expf(v.x - m), e1 = __expf(v.y - m);
    float s = e0 + e1;
    #pragma unroll
    for (int o = 32; o > 0; o >>= 1) s += __shfl_xor(s, o);
    if (ln == 0) reds[wid] = s;
    __syncthreads();
    s = reds[0] + reds[1] + reds[2] + reds[3];
    float rs = 1.0f / s;
    size_t o = (size_t)blockIdx.x * SKL + 2 * tid;
    wsplit(ph, pl, o,     e0 * rs);
    wsplit(ph, pl, o + 1, e1 * rs);
}

// ---------------------------------------------------------------------------
// Kernel 4: Vt = [v_mean | v_cov]^T per batch, bf16 hi/lo, [n][k] layout,
// zero-padded to NVT rows. LDS 32x32 tile transpose.
// ---------------------------------------------------------------------------
__global__ __launch_bounds__(256) void vsplit_kernel(
    const float* __restrict__ vmean, const float* __restrict__ vcov,
    ushort_t* __restrict__ vth, ushort_t* __restrict__ vtl)
{
    __shared__ float t[32][33];
    const int n0 = blockIdx.x * 32, k0 = blockIdx.y * 32, b = blockIdx.z;
    const int tx = threadIdx.x, ty = threadIdx.y;
    for (int r = ty; r < 32; r += 8) {              // r = k-offset; coalesced over tx=n
        const int k = k0 + r, n = n0 + tx;
        float v;
        if (n0 == 0)          v = vmean[((size_t)b * SKL + k) * DD + n];
        else if (n0 >= NOUT)  v = 0.f;
        else                  v = vcov[((size_t)b * SKL + k) * (DD * DD) + (n - DD)];
        t[tx][r] = v;
    }
    __syncthreads();
    for (int r = ty; r < 32; r += 8) {              // r = n-offset; coalesced over tx=k
        const int n = n0 + r, k = k0 + tx;
        const float v = t[r][tx];
        wsplit(vth, vtl, ((size_t)b * NVT + n) * SKL + k, v);
    }
}

// ---------------------------------------------------------------------------
extern "C" void kernel_launch(void* const* d_in, const int* in_sizes, int n_in,
                              void* d_out, int out_size, void* d_ws, size_t ws_size,
                              hipStream_t stream)
{
    const float* q_mean = (const float*)d_in[0];
    const float* q_cov  = (const float*)d_in[1];
    const float* k_mean = (const float*)d_in[2];
    const float* k_cov  = (const float*)d_in[3];
    const float* v_mean = (const float*)d_in[4];
    const float* v_cov  = (const float*)d_in[5];

    float* out_mean = (float*)d_out;                        // [8,512,32]
    float* out_cov  = out_mean + (size_t)NBATCH * SQL * DD; // [8,512,32,32]

    // workspace layout (46.1 MB):
    //   fq_h/fq_l | fk_h/fk_l (9.44MB each) | js 8.39MB
    // After score_gemm the feature arrays are dead:
    //   vt_h/vt_l alias fq_h/fq_l; p_h/p_l alias fk_h/fk_l
    char* w = (char*)d_ws;
    const size_t FQN = (size_t)NBATCH * SQL * KF;           // 4,718,592 elems
    ushort_t* fq_h = (ushort_t*)w;
    ushort_t* fq_l = fq_h + FQN;
    ushort_t* fk_h = fq_l + FQN;
    ushort_t* fk_l = fk_h + FQN;
    float*    js   = (float*)(fk_l + FQN);                  // 8*512*512 fp32
    ushort_t* vt_h = fq_h;
    ushort_t* vt_l = fq_l;
    ushort_t* p_h  = fk_h;
    ushort_t* p_l  = fk_l;

    feat_kernel<<<dim3(NBATCH * SQL, 2), 64, 0, stream>>>(
        q_mean, q_cov, k_mean, k_cov, fq_h, fq_l, fk_h, fk_l);
    gemm_split<KF, KF / 32, 0><<<dim3(SKL / 64, SQL / 128, NBATCH), 256, 0, stream>>>(
        fq_h, fq_l, fk_h, fk_l, js, nullptr);
    vsplit_kernel<<<dim3(NVT / 32, SKL / 32, NBATCH), dim3(32, 8), 0, stream>>>(
        v_mean, v_cov, vt_h, vt_l);
    softmax_rows<<<NBATCH * SQL, 256, 0, stream>>>(js, p_h, p_l);
    gemm_split<SKL, SKL / 32, 1><<<dim3(NVT / 64, SQL / 128, NBATCH), 256, 0, stream>>>(
        p_h, p_l, vt_h, vt_l, out_mean, out_cov);
}

// Round 4
// 225.145 us; speedup vs baseline: 1.6829x; 1.0124x over previous
//
#include <hip/hip_runtime.h>

#define NBATCH 8
#define SQL 512
#define SKL 512
#define DD 32
#define KF 1152            // padded feature dim (real 1121)
#define UT 528             // D*(D+1)/2
#define NOUT 1056          // 32 mean cols + 1024 cov cols
#define NVT 1088           // Vt rows padded to 17*64

typedef short short8 __attribute__((ext_vector_type(8)));   // 8 bf16 bit-patterns (4 VGPRs)
typedef float f32x4 __attribute__((ext_vector_type(4)));
typedef unsigned short ushort_t;

__device__ __forceinline__ ushort_t f2bf(float f) {          // fp32 -> bf16 bits, RNE
    unsigned int u = __float_as_uint(f);
    return (ushort_t)((u + 0x7fffu + ((u >> 16) & 1u)) >> 16);
}
__device__ __forceinline__ float bf2f(ushort_t h) {
    return __uint_as_float(((unsigned int)h) << 16);
}
__device__ __forceinline__ void wsplit(ushort_t* __restrict__ h, ushort_t* __restrict__ l,
                                       size_t idx, float v) {
    ushort_t hb = f2bf(v);
    h[idx] = hb;
    l[idx] = f2bf(v - bf2f(hb));
}
__device__ __forceinline__ float rdlane(float x, int l) {    // wave-uniform broadcast -> SGPR
    return __int_as_float(__builtin_amdgcn_readlane(__float_as_int(x), l));
}
__device__ __forceinline__ void gl_lds16(const ushort_t* g, ushort_t* l) {
    __builtin_amdgcn_global_load_lds(
        (const __attribute__((address_space(1))) void*)g,
        (__attribute__((address_space(3))) void*)l, 16, 0, 0);
}

// ---------------------------------------------------------------------------
// Kernel 1: per-site inversion + features. 4 matrices per 256-thread block
// (one per wave), sites 0..4095 = q-side, 4096..8191(x2) = k-side.
// Lane c holds augmented column c of [Cov | I]; pivot broadcasts via
// v_readlane (SGPR). LDS holds only inv/mu/iv per wave (17.9KB/block ->
// 8 blocks/CU -> 100% occupancy to hide the serial GJ chain).
// ---------------------------------------------------------------------------
__global__ __launch_bounds__(256, 8) void feat_kernel(
    const float* __restrict__ qm, const float* __restrict__ qc,
    const float* __restrict__ km, const float* __restrict__ kc,
    ushort_t* __restrict__ fqh, ushort_t* __restrict__ fql,
    ushort_t* __restrict__ fkh, ushort_t* __restrict__ fkl)
{
    const int wid = threadIdx.x >> 6;
    const int lane = threadIdx.x & 63;
    const int gsite = blockIdx.x * 4 + wid;        // 0..16383
    const int qside = gsite < NBATCH * SQL;
    const int site = qside ? gsite : gsite - NBATCH * SQL;

    const float* mean = qside ? qm : km;
    const float* cov  = qside ? qc : kc;
    ushort_t* fh = qside ? fqh : fkh;
    ushort_t* fl = qside ? fql : fkl;

    const float* covp = cov + (size_t)site * (DD * DD);
    const float* mup  = mean + (size_t)site * DD;
    const size_t fo = (size_t)site * KF;

    __shared__ float inv_s4[4][DD][DD + 1];
    __shared__ float mu_s4[4][DD];
    __shared__ float iv_s4[4][DD];
    float (*inv_s)[DD + 1] = inv_s4[wid];
    float* mu_s = mu_s4[wid];
    float* iv_s = iv_s4[wid];

    if (lane < DD) mu_s[lane] = mup[lane];

    float a[DD];
    if (lane < DD) {
        #pragma unroll
        for (int r = 0; r < DD; ++r) a[r] = covp[r * DD + lane];
    } else {
        const int c = lane - DD;
        #pragma unroll
        for (int r = 0; r < DD; ++r) a[r] = (r == c) ? 1.0f : 0.0f;
    }

    // Gauss-Jordan, no pivoting (SPD, cond ~2), wave-lockstep.
    #pragma unroll
    for (int p = 0; p < DD; ++p) {
        float piv = rdlane(a[p], p);
        float rinv = 1.0f / piv;
        float t = a[p] * rinv;
        #pragma unroll
        for (int r = 0; r < DD; ++r) {
            if (r != p) {
                float fr = rdlane(a[r], p);
                a[r] = fmaf(-fr, t, a[r]);
            }
        }
        a[p] = t;
    }

    if (lane >= DD) {
        const int c = lane - DD;
        #pragma unroll
        for (int r = 0; r < DD; ++r) inv_s[r][c] = a[r];
    }
    __syncthreads();

    if (lane < DD) {
        float s = 0.f;
        #pragma unroll
        for (int e = 0; e < DD; ++e) s += inv_s[lane][e] * mu_s[e];
        iv_s[lane] = s;                 // inv * mu
    }
    __syncthreads();

    float bias = 0.f;                   // mu^T inv mu
    #pragma unroll
    for (int d2 = 0; d2 < DD; ++d2) bias += mu_s[d2] * iv_s[d2];

    // Packed upper-triangle features. q-side carries the 0.25 JSD scale.
    for (int idx = lane; idx < UT; idx += 64) {
        int d = (int)((65.0f - sqrtf(4225.0f - 8.0f * (float)idx)) * 0.5f);
        if (d > 0 && (d * (65 - d)) / 2 > idx) --d;
        if (((d + 1) * (64 - d)) / 2 <= idx) ++d;
        int off = (d * (65 - d)) / 2;
        int e = d + (idx - off);
        float Mv = covp[d * DD + e] + mu_s[d] * mu_s[e];
        float Iv = 0.5f * (inv_s[d][e] + inv_s[e][d]);
        float w = (d == e) ? 0.25f : 0.5f;
        if (qside) { wsplit(fh, fl, fo + idx, w * Mv); wsplit(fh, fl, fo + UT + idx, w * Iv); }
        else       { wsplit(fh, fl, fo + idx, Iv);     wsplit(fh, fl, fo + UT + idx, Mv); }
    }
    if (lane < DD) {
        float ivv = iv_s[lane], muv = mu_s[lane];
        if (qside) { wsplit(fh, fl, fo + 2*UT + lane, -0.5f * ivv); wsplit(fh, fl, fo + 2*UT + DD + lane, 0.25f * muv); }
        else       { wsplit(fh, fl, fo + 2*UT + lane, muv);         wsplit(fh, fl, fo + 2*UT + DD + lane, -2.f * ivv); }
    }
    if (lane == 32) wsplit(fh, fl, fo + 2*UT + 2*DD, qside ? 0.25f : bias);
    for (int i = 2*UT + 2*DD + 1 + lane; i < KF; i += 64) { fh[fo + i] = 0; fl[fo + i] = 0; }
}

// ---------------------------------------------------------------------------
// Split-bf16 MFMA GEMM, global_load_lds(16B) staging into unpadded BK=32
// K-contiguous LDS rows (DMA requires base+lane*16 layout; m97-proven
// conflict-free for the b128 frag reads). Tile 128(M) x 64(N), 4 waves 2x2,
// each wave 64x32 via 4x2 mfma_f32_16x16x32_bf16.
// MODE 0: score, A split hi/lo (3 MFMA/pair), C0 = js fp32 (0.25 prefolded)
// MODE 1: output, A = P hi only (2 MFMA/pair), C0/C1 = out_mean/out_cov
// ---------------------------------------------------------------------------
template<int KSTRIDE, int KITERS, int MODE>
__global__ __launch_bounds__(256) void gemm_split(
    const ushort_t* __restrict__ Ah_g, const ushort_t* __restrict__ Al_g,
    const ushort_t* __restrict__ Bh_g, const ushort_t* __restrict__ Bl_g,
    float* __restrict__ C0, float* __restrict__ C1)
{
    constexpr bool ASPLIT = (MODE == 0);
    const int b = blockIdx.z, mt = blockIdx.y, nt = blockIdx.x;
    const int tid = threadIdx.x, lane = tid & 63, wid = tid >> 6;
    const int wm = wid & 1, wn = wid >> 1;
    const int BROWS = MODE ? NVT : SKL;

    const ushort_t* Ah = Ah_g + ((size_t)b * SQL + mt * 128) * KSTRIDE;
    const ushort_t* Al = Al_g + ((size_t)b * SQL + mt * 128) * KSTRIDE;
    const ushort_t* Bh = Bh_g + ((size_t)b * BROWS + nt * 64) * KSTRIDE;
    const ushort_t* Bl = Bl_g + ((size_t)b * BROWS + nt * 64) * KSTRIDE;

    __shared__ __align__(16) ushort_t AsH[128 * 32];
    __shared__ __align__(16) ushort_t AsL[ASPLIT ? 128 * 32 : 8];
    __shared__ __align__(16) ushort_t BsH[64 * 32];
    __shared__ __align__(16) ushort_t BsL[64 * 32];

    // DMA geometry: chunk c = 1024B = 16 rows; lane l covers row c*16+(l>>2),
    // elems (l&3)*8..+8; LDS dest = chunk_base + l*16 bytes (elem c*512+l*8).
    const int r4 = lane >> 2, kp = (lane & 3) * 8;
    const int arow0 = wid * 16 + r4,        aoff0 = wid * 512 + lane * 8;
    const int arow1 = (wid + 4) * 16 + r4,  aoff1 = (wid + 4) * 512 + lane * 8;

    const int fm = lane & 15;             // frag row (A) / col (B)
    const int q8 = (lane >> 4) * 8;       // frag K offset

    f32x4 acc[4][2];
    #pragma unroll
    for (int i = 0; i < 4; ++i)
        #pragma unroll
        for (int j = 0; j < 2; ++j)
            acc[i][j] = (f32x4){0.f, 0.f, 0.f, 0.f};

    for (int it = 0; it < KITERS; ++it) {
        const int k0 = it * 32;
        __syncthreads();                  // prior iter's frag reads complete
        gl_lds16(Ah + (size_t)arow0 * KSTRIDE + k0 + kp, &AsH[aoff0]);
        gl_lds16(Ah + (size_t)arow1 * KSTRIDE + k0 + kp, &AsH[aoff1]);
        if (ASPLIT) {
            gl_lds16(Al + (size_t)arow0 * KSTRIDE + k0 + kp, &AsL[aoff0]);
            gl_lds16(Al + (size_t)arow1 * KSTRIDE + k0 + kp, &AsL[aoff1]);
        }
        gl_lds16(Bh + (size_t)arow0 * KSTRIDE + k0 + kp, &BsH[aoff0]);
        gl_lds16(Bl + (size_t)arow0 * KSTRIDE + k0 + kp, &BsL[aoff0]);
        __syncthreads();                  // DMA drained (vmcnt at barrier)

        short8 ah[4], al[4], bh[2], bl[2];
        #pragma unroll
        for (int i = 0; i < 4; ++i) {
            const int r = wm * 64 + i * 16 + fm;
            ah[i] = *(const short8*)&AsH[r * 32 + q8];
            if (ASPLIT) al[i] = *(const short8*)&AsL[r * 32 + q8];
        }
        #pragma unroll
        for (int j = 0; j < 2; ++j) {
            const int r = wn * 32 + j * 16 + fm;
            bh[j] = *(const short8*)&BsH[r * 32 + q8];
            bl[j] = *(const short8*)&BsL[r * 32 + q8];
        }
        #pragma unroll
        for (int i = 0; i < 4; ++i)
            #pragma unroll
            for (int j = 0; j < 2; ++j) {
                acc[i][j] = __builtin_amdgcn_mfma_f32_16x16x32_bf16(ah[i], bh[j], acc[i][j], 0, 0, 0);
                acc[i][j] = __builtin_amdgcn_mfma_f32_16x16x32_bf16(ah[i], bl[j], acc[i][j], 0, 0, 0);
                if (ASPLIT)
                    acc[i][j] = __builtin_amdgcn_mfma_f32_16x16x32_bf16(al[i], bh[j], acc[i][j], 0, 0, 0);
            }
    }

    // Epilogue: C/D layout col=lane&15, row=(lane>>4)*4+reg (m89-verified)
    const int crow0 = (lane >> 4) * 4;
    const int ccol = lane & 15;
    #pragma unroll
    for (int i = 0; i < 4; ++i) {
        const int m = mt * 128 + wm * 64 + i * 16 + crow0;
        #pragma unroll
        for (int j = 0; j < 2; ++j) {
            const int n = nt * 64 + wn * 32 + j * 16 + ccol;
            #pragma unroll
            for (int r = 0; r < 4; ++r) {
                const float v = acc[i][j][r];
                const size_t rowb = (size_t)b * SQL + (m + r);
                if (MODE == 0) {
                    C0[rowb * SKL + n] = v;
                } else {
                    if (n < DD)        C0[rowb * DD + n] = v;
                    else if (n < NOUT) C1[rowb * (DD * DD) + (n - DD)] = v;
                }
            }
        }
    }
}

// ---------------------------------------------------------------------------
// Kernel 3: row softmax over 512-wide rows -> bf16 P (hi only; softmax
// weights are <=1 and sum to 1, so bf16 RNE adds <~8e-3 to outputs)
// ---------------------------------------------------------------------------
__global__ __launch_bounds__(256) void softmax_rows(
    const float* __restrict__ js, ushort_t* __restrict__ ph)
{
    const float* p = js + (size_t)blockIdx.x * SKL;
    const int tid = threadIdx.x;
    float2 v = *(const float2*)(p + 2 * tid);
    float m = fmaxf(v.x, v.y);
    #pragma unroll
    for (int o = 32; o > 0; o >>= 1) m = fmaxf(m, __shfl_xor(m, o));
    __shared__ float redm[4], reds[4];
    const int wid = tid >> 6, ln = tid & 63;
    if (ln == 0) redm[wid] = m;
    __syncthreads();
    m = fmaxf(fmaxf(redm[0], redm[1]), fmaxf(redm[2], redm[3]));
    float e0 = __expf(v.x - m), e1 = __expf(v.y - m);
    float s = e0 + e1;
    #pragma unroll
    for (int o = 32; o > 0; o >>= 1) s += __shfl_xor(s, o);
    if (ln == 0) reds[wid] = s;
    __syncthreads();
    s = reds[0] + reds[1] + reds[2] + reds[3];
    float rs = 1.0f / s;
    size_t o = (size_t)blockIdx.x * SKL + 2 * tid;
    ph[o]     = f2bf(e0 * rs);
    ph[o + 1] = f2bf(e1 * rs);
}

// ---------------------------------------------------------------------------
// Kernel 4: Vt = [v_mean | v_cov]^T per batch, bf16 hi/lo, [n][k] layout,
// zero-padded to NVT rows. LDS 32x32 tile transpose.
// ---------------------------------------------------------------------------
__global__ __launch_bounds__(256) void vsplit_kernel(
    const float* __restrict__ vmean, const float* __restrict__ vcov,
    ushort_t* __restrict__ vth, ushort_t* __restrict__ vtl)
{
    __shared__ float t[32][33];
    const int n0 = blockIdx.x * 32, k0 = blockIdx.y * 32, b = blockIdx.z;
    const int tx = threadIdx.x, ty = threadIdx.y;
    for (int r = ty; r < 32; r += 8) {              // r = k-offset; coalesced over tx=n
        const int k = k0 + r, n = n0 + tx;
        float v;
        if (n0 == 0)          v = vmean[((size_t)b * SKL + k) * DD + n];
        else if (n0 >= NOUT)  v = 0.f;
        else                  v = vcov[((size_t)b * SKL + k) * (DD * DD) + (n - DD)];
        t[tx][r] = v;
    }
    __syncthreads();
    for (int r = ty; r < 32; r += 8) {              // r = n-offset; coalesced over tx=k
        const int n = n0 + r, k = k0 + tx;
        const float v = t[r][tx];
        wsplit(vth, vtl, ((size_t)b * NVT + n) * SKL + k, v);
    }
}

// ---------------------------------------------------------------------------
extern "C" void kernel_launch(void* const* d_in, const int* in_sizes, int n_in,
                              void* d_out, int out_size, void* d_ws, size_t ws_size,
                              hipStream_t stream)
{
    const float* q_mean = (const float*)d_in[0];
    const float* q_cov  = (const float*)d_in[1];
    const float* k_mean = (const float*)d_in[2];
    const float* k_cov  = (const float*)d_in[3];
    const float* v_mean = (const float*)d_in[4];
    const float* v_cov  = (const float*)d_in[5];

    float* out_mean = (float*)d_out;                        // [8,512,32]
    float* out_cov  = out_mean + (size_t)NBATCH * SQL * DD; // [8,512,32,32]

    // workspace layout (46.1 MB):
    //   fq_h/fq_l | fk_h/fk_l (9.44MB each) | js 8.39MB
    // After score_gemm the feature arrays are dead:
    //   vt_h/vt_l alias fq_h/fq_l; p_h aliases fk_h
    char* w = (char*)d_ws;
    const size_t FQN = (size_t)NBATCH * SQL * KF;           // 4,718,592 elems
    ushort_t* fq_h = (ushort_t*)w;
    ushort_t* fq_l = fq_h + FQN;
    ushort_t* fk_h = fq_l + FQN;
    ushort_t* fk_l = fk_h + FQN;
    float*    js   = (float*)(fk_l + FQN);                  // 8*512*512 fp32
    ushort_t* vt_h = fq_h;
    ushort_t* vt_l = fq_l;
    ushort_t* p_h  = fk_h;

    feat_kernel<<<dim3(2 * NBATCH * SQL / 4), 256, 0, stream>>>(
        q_mean, q_cov, k_mean, k_cov, fq_h, fq_l, fk_h, fk_l);
    gemm_split<KF, KF / 32, 0><<<dim3(SKL / 64, SQL / 128, NBATCH), 256, 0, stream>>>(
        fq_h, fq_l, fk_h, fk_l, js, nullptr);
    vsplit_kernel<<<dim3(NVT / 32, SKL / 32, NBATCH), dim3(32, 8), 0, stream>>>(
        v_mean, v_cov, vt_h, vt_l);
    softmax_rows<<<NBATCH * SQL, 256, 0, stream>>>(js, p_h);
    gemm_split<SKL, SKL / 32, 1><<<dim3(NVT / 64, SQL / 128, NBATCH), 256, 0, stream>>>(
        p_h, nullptr, vt_h, vt_l, out_mean, out_cov);
}

// Round 5
// 217.970 us; speedup vs baseline: 1.7383x; 1.0329x over previous
//
#include <hip/hip_runtime.h>
#include <hip/hip_bf16.h>

#define NBATCH 8
#define SQL 512
#define SKL 512
#define DD 32
#define KF 1152            // padded feature dim (real 1121)
#define UT 528             // D*(D+1)/2
#define NOUT 1056          // 32 mean cols + 1024 cov cols
#define NVT 1088           // Vt rows padded to 17*64
#define NSITE (NBATCH * SQL)        // 4096 per side
#define FEAT_BLOCKS (2 * NSITE / 4) // 4096 blocks, 4 sites each
#define VS_BLOCKS (34 * 16 * NBATCH)

typedef short short8 __attribute__((ext_vector_type(8)));   // 8 bf16 bit-patterns
typedef float f32x4 __attribute__((ext_vector_type(4)));
typedef unsigned short ushort_t;

__device__ __forceinline__ ushort_t f2bf(float f) {          // fp32 -> bf16 bits, RNE
    unsigned int u = __float_as_uint(f);
    return (ushort_t)((u + 0x7fffu + ((u >> 16) & 1u)) >> 16);
}
__device__ __forceinline__ float bf2f(ushort_t h) {
    return __uint_as_float(((unsigned int)h) << 16);
}
__device__ __forceinline__ float rdlane(float x, int l) {    // wave-uniform broadcast -> SGPR
    return __int_as_float(__builtin_amdgcn_readlane(__float_as_int(x), l));
}
__device__ __forceinline__ void gl_lds16(const ushort_t* g, ushort_t* l) {
    __builtin_amdgcn_global_load_lds(
        (const __attribute__((address_space(1))) void*)g,
        (__attribute__((address_space(3))) void*)l, 16, 0, 0);
}
// packed 2x fp32 -> bf16 hi bits + lo residual bits (v_cvt_pk_bf16_f32 path)
__device__ __forceinline__ void pk_split(float v0, float v1, ushort_t& h0, ushort_t& h1,
                                         ushort_t& l0, ushort_t& l1) {
    __hip_bfloat162 H = __float22bfloat162_rn(make_float2(v0, v1));
    ushort2 hu = *(ushort2*)&H;
    h0 = hu.x; h1 = hu.y;
    __hip_bfloat162 L = __float22bfloat162_rn(make_float2(v0 - bf2f(hu.x), v1 - bf2f(hu.y)));
    ushort2 lu = *(ushort2*)&L;
    l0 = lu.x; l1 = lu.y;
}

// ---------------------------------------------------------------------------
// Kernel 1: per-site inversion + features. 4 matrices per 256-thread block
// (one per wave). Augmented [Cov|I] GJ, lane c = column c, pivot broadcasts
// via v_readlane (SGPR; readlane:FMA 1:1, both VALU — DS-swizzle variants
// lose on the 1-per-CU DS pipe). Inverse stored as packed upper triangle
// (560 floats/wave -> 10KB/block for occupancy).
// ---------------------------------------------------------------------------
__global__ __launch_bounds__(256, 8) void feat_kernel(
    const float* __restrict__ qm, const float* __restrict__ qc,
    const float* __restrict__ km, const float* __restrict__ kc,
    ushort_t* __restrict__ fqh, ushort_t* __restrict__ fql,
    ushort_t* __restrict__ fkh, ushort_t* __restrict__ fkl)
{
    __shared__ float smem[4 * 624];   // per wave: 560 packed inv + 32 mu + 32 iv
    const int wid = threadIdx.x >> 6;
    const int lane = threadIdx.x & 63;
    const int gsite = blockIdx.x * 4 + wid;        // 0..8191
    const int qside = gsite < NSITE;
    const int site = qside ? gsite : gsite - NSITE;

    const float* mean = qside ? qm : km;
    const float* cov  = qside ? qc : kc;
    ushort_t* fh = qside ? fqh : fkh;
    ushort_t* fl = qside ? fql : fkl;

    const float* covp = cov + (size_t)site * (DD * DD);
    const float* mup  = mean + (size_t)site * DD;
    const size_t fo = (size_t)site * KF;

    float* inv_p = smem + wid * 624;
    float* mu_s  = inv_p + 560;
    float* iv_s  = mu_s + 32;

    if (lane < DD) mu_s[lane] = mup[lane];

    float a[DD];
    if (lane < DD) {
        #pragma unroll
        for (int r = 0; r < DD; ++r) a[r] = covp[r * DD + lane];
    } else {
        const int c = lane - DD;
        #pragma unroll
        for (int r = 0; r < DD; ++r) a[r] = (r == c) ? 1.0f : 0.0f;
    }

    // Gauss-Jordan, no pivoting (SPD, cond ~2), wave-lockstep.
    #pragma unroll
    for (int p = 0; p < DD; ++p) {
        float piv = rdlane(a[p], p);
        float rinv = 1.0f / piv;
        float t = a[p] * rinv;
        #pragma unroll
        for (int r = 0; r < DD; ++r) {
            if (r != p) {
                float fr = rdlane(a[r], p);
                a[r] = fmaf(-fr, t, a[r]);
            }
        }
        a[p] = t;
    }

    // Store inverse upper triangle packed: idx(d,e)=d*(65-d)/2+(e-d), d<=e
    if (lane >= DD) {
        const int c = lane - DD;
        #pragma unroll
        for (int r = 0; r < DD; ++r)
            if (r <= c) inv_p[((r * (65 - r)) >> 1) + (c - r)] = a[r];
    }
    __syncthreads();

    // iv = Sigma^-1 mu via packed symmetric reads
    {
        const int j = lane & 31;
        const int basej = (j * (65 - j)) >> 1;
        float s = 0.f;
        #pragma unroll
        for (int e = 0; e < DD; ++e) {
            const int be = (e * (65 - e)) >> 1;
            const int addr = (e < j) ? (be + (j - e)) : (basej + (e - j));
            s += inv_p[addr] * mu_s[e];
        }
        if (lane < DD) iv_s[lane] = s;
    }
    __syncthreads();

    float bias = 0.f;                   // mu^T Sigma^-1 mu
    #pragma unroll
    for (int d2 = 0; d2 < DD; ++d2) bias += mu_s[d2] * iv_s[d2];

    // Packed upper-triangle features (q-side carries the 0.25 JSD scale).
    for (int idx = lane; idx < UT; idx += 64) {
        int d = (int)((65.0f - sqrtf(4225.0f - 8.0f * (float)idx)) * 0.5f);
        if (d > 0 && (d * (65 - d)) / 2 > idx) --d;
        if (((d + 1) * (64 - d)) / 2 <= idx) ++d;
        int off = (d * (65 - d)) / 2;
        int e = d + (idx - off);
        float Mv = covp[d * DD + e] + mu_s[d] * mu_s[e];
        float Iv = inv_p[idx];
        float w = (d == e) ? 0.25f : 0.5f;
        float v0, v1;
        if (qside) { v0 = w * Mv; v1 = w * Iv; }
        else       { v0 = Iv;     v1 = Mv; }
        ushort_t h0, h1, l0, l1;
        pk_split(v0, v1, h0, h1, l0, l1);
        fh[fo + idx] = h0; fh[fo + UT + idx] = h1;
        fl[fo + idx] = l0; fl[fo + UT + idx] = l1;
    }
    if (lane < DD) {
        float ivv = iv_s[lane], muv = mu_s[lane];
        float v0, v1;
        if (qside) { v0 = -0.5f * ivv; v1 = 0.25f * muv; }
        else       { v0 = muv;         v1 = -2.f * ivv; }
        ushort_t h0, h1, l0, l1;
        pk_split(v0, v1, h0, h1, l0, l1);
        fh[fo + 2*UT + lane] = h0; fh[fo + 2*UT + DD + lane] = h1;
        fl[fo + 2*UT + lane] = l0; fl[fo + 2*UT + DD + lane] = l1;
    }
    if (lane == 32) {
        float v = qside ? 0.25f : bias;
        ushort_t hb = f2bf(v);
        fh[fo + 2*UT + 2*DD] = hb;
        fl[fo + 2*UT + 2*DD] = f2bf(v - bf2f(hb));
    }
    for (int i = 2*UT + 2*DD + 1 + lane; i < KF; i += 64) { fh[fo + i] = 0; fl[fo + i] = 0; }
}

// ---------------------------------------------------------------------------
// MFMA GEMM, global_load_lds(16B) staging, unpadded BK=32 K-contiguous LDS
// rows. Tile 128(M) x 64(N), 4 waves 2x2, each wave 64x32 via 4x2
// mfma_f32_16x16x32_bf16.
// MODE 0: score. A,B split hi/lo (3 MFMA/pair). Split-K x2 (grid.y packs
//         mt + kslice), epilogue atomicAdd into pre-zeroed js.
// MODE 1: output. A=P hi, B=Vt hi (1 MFMA/pair; residuals bounded by
//         softmax convexity + |v|*2^-9). Routed stores.
// ---------------------------------------------------------------------------
template<int MODE>
__global__ __launch_bounds__(256) void gemm_split(
    const ushort_t* __restrict__ Ah_g, const ushort_t* __restrict__ Al_g,
    const ushort_t* __restrict__ Bh_g, const ushort_t* __restrict__ Bl_g,
    float* __restrict__ C0, float* __restrict__ C1)
{
    constexpr bool SPLIT = (MODE == 0);
    constexpr int KSTRIDE = SPLIT ? KF : SKL;
    constexpr int KITERS = SPLIT ? (KF / 2 / 32) : (SKL / 32);
    const int b = blockIdx.z, nt = blockIdx.x;
    const int mt = SPLIT ? (blockIdx.y & 3) : blockIdx.y;
    const int kbase = SPLIT ? ((blockIdx.y >> 2) * (KF / 2)) : 0;
    const int tid = threadIdx.x, lane = tid & 63, wid = tid >> 6;
    const int wm = wid & 1, wn = wid >> 1;
    const int BROWS = MODE ? NVT : SKL;

    const ushort_t* Ah = Ah_g + ((size_t)b * SQL + mt * 128) * KSTRIDE;
    const ushort_t* Al = Al_g + ((size_t)b * SQL + mt * 128) * KSTRIDE;
    const ushort_t* Bh = Bh_g + ((size_t)b * BROWS + nt * 64) * KSTRIDE;
    const ushort_t* Bl = Bl_g + ((size_t)b * BROWS + nt * 64) * KSTRIDE;

    __shared__ __align__(16) ushort_t AsH[128 * 32];
    __shared__ __align__(16) ushort_t AsL[SPLIT ? 128 * 32 : 8];
    __shared__ __align__(16) ushort_t BsH[64 * 32];
    __shared__ __align__(16) ushort_t BsL[SPLIT ? 64 * 32 : 8];

    // DMA geometry: chunk = 1024B = 16 rows; lane l covers row c*16+(l>>2),
    // elems (l&3)*8..+8; LDS dest = chunk_base + l*16 bytes.
    const int r4 = lane >> 2, kp = (lane & 3) * 8;
    const int arow0 = wid * 16 + r4,        aoff0 = wid * 512 + lane * 8;
    const int arow1 = (wid + 4) * 16 + r4,  aoff1 = (wid + 4) * 512 + lane * 8;

    const int fm = lane & 15;             // frag row (A) / col (B)
    const int q8 = (lane >> 4) * 8;       // frag K offset

    f32x4 acc[4][2];
    #pragma unroll
    for (int i = 0; i < 4; ++i)
        #pragma unroll
        for (int j = 0; j < 2; ++j)
            acc[i][j] = (f32x4){0.f, 0.f, 0.f, 0.f};

    for (int it = 0; it < KITERS; ++it) {
        const int k0 = kbase + it * 32;
        __syncthreads();                  // prior iter's frag reads complete
        gl_lds16(Ah + (size_t)arow0 * KSTRIDE + k0 + kp, &AsH[aoff0]);
        gl_lds16(Ah + (size_t)arow1 * KSTRIDE + k0 + kp, &AsH[aoff1]);
        gl_lds16(Bh + (size_t)arow0 * KSTRIDE + k0 + kp, &BsH[aoff0]);
        if (SPLIT) {
            gl_lds16(Al + (size_t)arow0 * KSTRIDE + k0 + kp, &AsL[aoff0]);
            gl_lds16(Al + (size_t)arow1 * KSTRIDE + k0 + kp, &AsL[aoff1]);
            gl_lds16(Bl + (size_t)arow0 * KSTRIDE + k0 + kp, &BsL[aoff0]);
        }
        __syncthreads();                  // DMA drained (vmcnt at barrier)

        short8 ah[4], al[4], bh[2], bl[2];
        #pragma unroll
        for (int i = 0; i < 4; ++i) {
            const int r = wm * 64 + i * 16 + fm;
            ah[i] = *(const short8*)&AsH[r * 32 + q8];
            if (SPLIT) al[i] = *(const short8*)&AsL[r * 32 + q8];
        }
        #pragma unroll
        for (int j = 0; j < 2; ++j) {
            const int r = wn * 32 + j * 16 + fm;
            bh[j] = *(const short8*)&BsH[r * 32 + q8];
            if (SPLIT) bl[j] = *(const short8*)&BsL[r * 32 + q8];
        }
        #pragma unroll
        for (int i = 0; i < 4; ++i)
            #pragma unroll
            for (int j = 0; j < 2; ++j) {
                acc[i][j] = __builtin_amdgcn_mfma_f32_16x16x32_bf16(ah[i], bh[j], acc[i][j], 0, 0, 0);
                if (SPLIT) {
                    acc[i][j] = __builtin_amdgcn_mfma_f32_16x16x32_bf16(ah[i], bl[j], acc[i][j], 0, 0, 0);
                    acc[i][j] = __builtin_amdgcn_mfma_f32_16x16x32_bf16(al[i], bh[j], acc[i][j], 0, 0, 0);
                }
            }
    }

    // Epilogue: C/D layout col=lane&15, row=(lane>>4)*4+reg (m89-verified)
    const int crow0 = (lane >> 4) * 4;
    const int ccol = lane & 15;
    #pragma unroll
    for (int i = 0; i < 4; ++i) {
        const int m = mt * 128 + wm * 64 + i * 16 + crow0;
        #pragma unroll
        for (int j = 0; j < 2; ++j) {
            const int n = nt * 64 + wn * 32 + j * 16 + ccol;
            #pragma unroll
            for (int r = 0; r < 4; ++r) {
                const float v = acc[i][j][r];
                const size_t rowb = (size_t)b * SQL + (m + r);
                if (MODE == 0) {
                    atomicAdd(&C0[rowb * SKL + n], v);
                } else {
                    if (n < DD)        C0[rowb * DD + n] = v;
                    else if (n < NOUT) C1[rowb * (DD * DD) + (n - DD)] = v;
                }
            }
        }
    }
}

// ---------------------------------------------------------------------------
// Kernel 3 (merged): blocks [0, 4096): row softmax js -> bf16 P (hi only).
// blocks [4096, ..): Vt = [v_mean | v_cov]^T, bf16 hi, [n][k], zero-padded
// to NVT rows, via LDS 32x32 transpose.
// ---------------------------------------------------------------------------
__global__ __launch_bounds__(256) void phase2_kernel(
    const float* __restrict__ js, ushort_t* __restrict__ ph,
    const float* __restrict__ vmean, const float* __restrict__ vcov,
    ushort_t* __restrict__ vth)
{
    __shared__ float sm[32 * 33];
    const int tid = threadIdx.x;
    if (blockIdx.x < (unsigned)(NBATCH * SQL)) {
        const float* p = js + (size_t)blockIdx.x * SKL;
        float2 v = *(const float2*)(p + 2 * tid);
        float m = fmaxf(v.x, v.y);
        #pragma unroll
        for (int o = 32; o > 0; o >>= 1) m = fmaxf(m, __shfl_xor(m, o));
        const int wid = tid >> 6, ln = tid & 63;
        if (ln == 0) sm[wid] = m;
        __syncthreads();
        m = fmaxf(fmaxf(sm[0], sm[1]), fmaxf(sm[2], sm[3]));
        float e0 = __expf(v.x - m), e1 = __expf(v.y - m);
        float s = e0 + e1;
        #pragma unroll
        for (int o = 32; o > 0; o >>= 1) s += __shfl_xor(s, o);
        if (ln == 0) sm[4 + wid] = s;
        __syncthreads();
        s = sm[4] + sm[5] + sm[6] + sm[7];
        float rs = 1.0f / s;
        size_t o = (size_t)blockIdx.x * SKL + 2 * tid;
        ph[o]     = f2bf(e0 * rs);
        ph[o + 1] = f2bf(e1 * rs);
    } else {
        const int vb = blockIdx.x - NBATCH * SQL;
        const int b = vb / (34 * 16), rem = vb % (34 * 16);
        const int kt = rem / 34, nt = rem % 34;
        const int n0 = nt * 32, k0 = kt * 32;
        const int tx = tid & 31, ty = tid >> 5;
        for (int r = ty; r < 32; r += 8) {          // r = k-offset; coalesced over tx=n
            const int k = k0 + r, n = n0 + tx;
            float v;
            if (n0 == 0)          v = vmean[((size_t)b * SKL + k) * DD + n];
            else if (n0 >= NOUT)  v = 0.f;
            else                  v = vcov[((size_t)b * SKL + k) * (DD * DD) + (n - DD)];
            sm[tx * 33 + r] = v;
        }
        __syncthreads();
        for (int r = ty; r < 32; r += 8) {          // r = n-offset; coalesced over tx=k
            const int n = n0 + r, k = k0 + tx;
            vth[((size_t)b * NVT + n) * SKL + k] = f2bf(sm[r * 33 + tx]);
        }
    }
}

// ---------------------------------------------------------------------------
extern "C" void kernel_launch(void* const* d_in, const int* in_sizes, int n_in,
                              void* d_out, int out_size, void* d_ws, size_t ws_size,
                              hipStream_t stream)
{
    const float* q_mean = (const float*)d_in[0];
    const float* q_cov  = (const float*)d_in[1];
    const float* k_mean = (const float*)d_in[2];
    const float* k_cov  = (const float*)d_in[3];
    const float* v_mean = (const float*)d_in[4];
    const float* v_cov  = (const float*)d_in[5];

    float* out_mean = (float*)d_out;                        // [8,512,32]
    float* out_cov  = out_mean + (size_t)NBATCH * SQL * DD; // [8,512,32,32]

    // workspace (46.1 MB): fq_h/fq_l | fk_h/fk_l (9.44MB each) | js 8.39MB
    // After score gemm the feature arrays are dead:
    //   vt_h aliases fq_h; p_h aliases fk_h
    char* w = (char*)d_ws;
    const size_t FQN = (size_t)NBATCH * SQL * KF;           // 4,718,592 elems
    ushort_t* fq_h = (ushort_t*)w;
    ushort_t* fq_l = fq_h + FQN;
    ushort_t* fk_h = fq_l + FQN;
    ushort_t* fk_l = fk_h + FQN;
    float*    js   = (float*)(fk_l + FQN);                  // 8*512*512 fp32
    ushort_t* vt_h = fq_h;
    ushort_t* p_h  = fk_h;

    feat_kernel<<<FEAT_BLOCKS, 256, 0, stream>>>(
        q_mean, q_cov, k_mean, k_cov, fq_h, fq_l, fk_h, fk_l);
    hipMemsetAsync(js, 0, (size_t)NBATCH * SQL * SKL * sizeof(float), stream);
    gemm_split<0><<<dim3(SKL / 64, 8, NBATCH), 256, 0, stream>>>(
        fq_h, fq_l, fk_h, fk_l, js, nullptr);
    phase2_kernel<<<NBATCH * SQL + VS_BLOCKS, 256, 0, stream>>>(
        js, p_h, v_mean, v_cov, vt_h);
    gemm_split<1><<<dim3(NVT / 64, SQL / 128, NBATCH), 256, 0, stream>>>(
        p_h, nullptr, vt_h, nullptr, out_mean, out_cov);
}

// Round 6
// 190.326 us; speedup vs baseline: 1.9908x; 1.1452x over previous
//
#include <hip/hip_runtime.h>
#include <hip/hip_bf16.h>

#define NBATCH 8
#define SQL 512
#define SKL 512
#define DD 32
#define KF 1152            // padded feature dim (real 1121)
#define UT 528             // D*(D+1)/2
#define NOUT 1056          // 32 mean cols + 1024 cov cols
#define NVT 1088           // Vt rows padded to 17*64
#define NSITE (NBATCH * SQL)        // 4096 per side
#define VS_BLOCKS (34 * 16 * NBATCH)

typedef short short8 __attribute__((ext_vector_type(8)));   // 8 bf16 bit-patterns
typedef float f32x4 __attribute__((ext_vector_type(4)));
typedef unsigned short ushort_t;

__device__ __forceinline__ ushort_t f2bf(float f) {          // fp32 -> bf16 bits, RNE
    unsigned int u = __float_as_uint(f);
    return (ushort_t)((u + 0x7fffu + ((u >> 16) & 1u)) >> 16);
}
__device__ __forceinline__ float bf2f(ushort_t h) {
    return __uint_as_float(((unsigned int)h) << 16);
}
__device__ __forceinline__ void gl_lds16(const ushort_t* g, ushort_t* l) {
    __builtin_amdgcn_global_load_lds(
        (const __attribute__((address_space(1))) void*)g,
        (__attribute__((address_space(3))) void*)l, 16, 0, 0);
}
// packed 2x fp32 -> bf16 hi bits + lo residual bits
__device__ __forceinline__ void pk_split(float v0, float v1, ushort_t& h0, ushort_t& h1,
                                         ushort_t& l0, ushort_t& l1) {
    __hip_bfloat162 H = __float22bfloat162_rn(make_float2(v0, v1));
    ushort2 hu = *(ushort2*)&H;
    h0 = hu.x; h1 = hu.y;
    __hip_bfloat162 L = __float22bfloat162_rn(make_float2(v0 - bf2f(hu.x), v1 - bf2f(hu.y)));
    ushort2 lu = *(ushort2*)&L;
    l0 = lu.x; l1 = lu.y;
}

// ds_swizzle BitMode broadcast of lane P within each 32-lane half:
// offset = (xor<<10)|(or<<5)|and, and=0 or=P xor=0 -> src lane = P per group.
template<int P>
__device__ __forceinline__ float swzb(float x) {
    return __int_as_float(__builtin_amdgcn_ds_swizzle(__float_as_int(x), (P << 5)));
}
// butterfly xor-M within each 32-lane half (and=0x1F)
template<int M>
__device__ __forceinline__ float swzx(float x) {
    return __int_as_float(__builtin_amdgcn_ds_swizzle(__float_as_int(x), (M << 10) | 0x1F));
}

// In-place symmetric GJ sweep, one pivot. Lane hl (0..31 per half) holds
// column hl. After all 32 pivots, a[] = column hl of A^-1.
// b_pp=1/d; b_pj=a_pj/d; b_ip=-a_ip/d; b_ij=a_ij-a_ip*a_pj/d.
template<int P>
__device__ __forceinline__ void gj_step(float (&a)[DD], int hl) {
    float piv = swzb<P>(a[P]);
    float rinv = __builtin_amdgcn_rcpf(piv);   // SPD, cond~2: 1-ulp rcp fine
    float t = a[P] * rinv;
    bool isp = (hl == P);
    float u = isp ? rinv : t;                  // lane P: 1/d path
    float g = isp ? 0.0f : 1.0f;               // lane P: kill a[i] term
    #pragma unroll
    for (int i = 0; i < DD; ++i) {
        if (i == P) continue;
        float ci = swzb<P>(a[i]);              // a_iP (per half), pre-update
        a[i] = fmaf(a[i], g, -(ci * u));       // lane!=P: a-ci*t; lane P: -ci*rinv
    }
    a[P] = u;
}
template<int P>
__device__ __forceinline__ void gj_run(float (&a)[DD], int hl) {
    gj_step<P>(a, hl);
    if constexpr (P + 1 < DD) gj_run<P + 1>(a, hl);
}

// ---------------------------------------------------------------------------
// Kernel 1: per-site inversion + features. TWO matrices per wave (lanes 0-31
// = site s, 32-63 = site s+1), in-place symmetric GJ with ds_swizzle
// half-broadcasts (DS pipe, no readlane SGPR hazards). All LDS wave-private
// -> no barriers. 8 matrices per 256-thread block.
// ---------------------------------------------------------------------------
__global__ __launch_bounds__(256, 4) void feat_kernel(
    const float* __restrict__ qm, const float* __restrict__ qc,
    const float* __restrict__ km, const float* __restrict__ kc,
    ushort_t* __restrict__ fqh, ushort_t* __restrict__ fql,
    ushort_t* __restrict__ fkh, ushort_t* __restrict__ fkl)
{
    __shared__ float inv2[8 * 1064];   // per matrix: 32x33 padded inverse
    __shared__ float mu2[8 * 32];

    const int tid = threadIdx.x;
    const int wid = tid >> 6, lane = tid & 63;
    const int half = lane >> 5, hl = lane & 31;
    const int site_g = (blockIdx.x * 4 + wid) * 2 + half;   // 0..8191
    const int qside = site_g < NSITE;
    const int site = qside ? site_g : site_g - NSITE;

    const float* covp = (qside ? qc : kc) + (size_t)site * (DD * DD);
    const float* mup  = (qside ? qm : km) + (size_t)site * DD;
    ushort_t* fh = qside ? fqh : fkh;
    ushort_t* fl = qside ? fql : fkl;
    const size_t fo = (size_t)site * KF;

    float* inv_s = inv2 + (wid * 2 + half) * 1064;   // row stride 33
    float* mu_s  = mu2 + (wid * 2 + half) * 32;

    const float mu_lane = mup[hl];
    mu_s[hl] = mu_lane;

    float a[DD];
    #pragma unroll
    for (int r = 0; r < DD; ++r) a[r] = covp[r * DD + hl];

    gj_run<0>(a, hl);                  // a[] = column hl of Sigma^-1

    // dump inverse (own column) to wave-private LDS
    #pragma unroll
    for (int r = 0; r < DD; ++r) inv_s[r * 33 + hl] = a[r];

    // iv_c = (Sigma^-1 mu)_c from own column (symmetry) + LDS mu broadcasts
    float ivr = 0.f;
    #pragma unroll
    for (int e = 0; e < DD; ++e) ivr = fmaf(a[e], mu_s[e], ivr);

    // bias = mu^T Sigma^-1 mu : butterfly sum within half
    float pb = mu_lane * ivr;
    pb += swzx<1>(pb); pb += swzx<2>(pb); pb += swzx<4>(pb);
    pb += swzx<8>(pb); pb += swzx<16>(pb);
    const float bias = pb;

    // Packed upper-triangle features (q-side carries the 0.25 JSD scale).
    for (int idx = hl; idx < UT; idx += 32) {
        int d = (int)((65.0f - sqrtf(4225.0f - 8.0f * (float)idx)) * 0.5f);
        if (d > 0 && (d * (65 - d)) / 2 > idx) --d;
        if (((d + 1) * (64 - d)) / 2 <= idx) ++d;
        int off = (d * (65 - d)) / 2;
        int e = d + (idx - off);
        float Mv = covp[d * DD + e] + mu_s[d] * mu_s[e];
        float Iv = inv_s[d * 33 + e];
        float w = (d == e) ? 0.25f : 0.5f;
        float v0, v1;
        if (qside) { v0 = w * Mv; v1 = w * Iv; }
        else       { v0 = Iv;     v1 = Mv; }
        ushort_t h0, h1, l0, l1;
        pk_split(v0, v1, h0, h1, l0, l1);
        fh[fo + idx] = h0; fh[fo + UT + idx] = h1;
        fl[fo + idx] = l0; fl[fo + UT + idx] = l1;
    }
    {
        float v0, v1;
        if (qside) { v0 = -0.5f * ivr; v1 = 0.25f * mu_lane; }
        else       { v0 = mu_lane;     v1 = -2.f * ivr; }
        ushort_t h0, h1, l0, l1;
        pk_split(v0, v1, h0, h1, l0, l1);
        fh[fo + 2*UT + hl] = h0; fh[fo + 2*UT + DD + hl] = h1;
        fl[fo + 2*UT + hl] = l0; fl[fo + 2*UT + DD + hl] = l1;
    }
    if (hl == 0) {
        float v = qside ? 0.25f : bias;
        ushort_t hb = f2bf(v);
        fh[fo + 2*UT + 2*DD] = hb;
        fl[fo + 2*UT + 2*DD] = f2bf(v - bf2f(hb));
    }
    for (int i = 2*UT + 2*DD + 1 + hl; i < KF; i += 32) { fh[fo + i] = 0; fl[fo + i] = 0; }
}

// ---------------------------------------------------------------------------
// MFMA GEMM, global_load_lds(16B) staging, unpadded BK=32 K-contiguous LDS
// rows. Tile 128(M) x 64(N), 4 waves 2x2, each wave 64x32 via 4x2
// mfma_f32_16x16x32_bf16.
// MODE 0: score. A,B split hi/lo (3 MFMA/pair). Split-K x2, atomicAdd
//         epilogue into pre-zeroed js.
// MODE 1: output. A=P hi, B=Vt hi (residuals bounded by softmax convexity).
// ---------------------------------------------------------------------------
template<int MODE>
__global__ __launch_bounds__(256) void gemm_split(
    const ushort_t* __restrict__ Ah_g, const ushort_t* __restrict__ Al_g,
    const ushort_t* __restrict__ Bh_g, const ushort_t* __restrict__ Bl_g,
    float* __restrict__ C0, float* __restrict__ C1)
{
    constexpr bool SPLIT = (MODE == 0);
    constexpr int KSTRIDE = SPLIT ? KF : SKL;
    constexpr int KITERS = SPLIT ? (KF / 2 / 32) : (SKL / 32);
    const int b = blockIdx.z, nt = blockIdx.x;
    const int mt = SPLIT ? (blockIdx.y & 3) : blockIdx.y;
    const int kbase = SPLIT ? ((blockIdx.y >> 2) * (KF / 2)) : 0;
    const int tid = threadIdx.x, lane = tid & 63, wid = tid >> 6;
    const int wm = wid & 1, wn = wid >> 1;
    const int BROWS = MODE ? NVT : SKL;

    const ushort_t* Ah = Ah_g + ((size_t)b * SQL + mt * 128) * KSTRIDE;
    const ushort_t* Al = Al_g + ((size_t)b * SQL + mt * 128) * KSTRIDE;
    const ushort_t* Bh = Bh_g + ((size_t)b * BROWS + nt * 64) * KSTRIDE;
    const ushort_t* Bl = Bl_g + ((size_t)b * BROWS + nt * 64) * KSTRIDE;

    __shared__ __align__(16) ushort_t AsH[128 * 32];
    __shared__ __align__(16) ushort_t AsL[SPLIT ? 128 * 32 : 8];
    __shared__ __align__(16) ushort_t BsH[64 * 32];
    __shared__ __align__(16) ushort_t BsL[SPLIT ? 64 * 32 : 8];

    const int r4 = lane >> 2, kp = (lane & 3) * 8;
    const int arow0 = wid * 16 + r4,        aoff0 = wid * 512 + lane * 8;
    const int arow1 = (wid + 4) * 16 + r4,  aoff1 = (wid + 4) * 512 + lane * 8;

    const int fm = lane & 15;
    const int q8 = (lane >> 4) * 8;

    f32x4 acc[4][2];
    #pragma unroll
    for (int i = 0; i < 4; ++i)
        #pragma unroll
        for (int j = 0; j < 2; ++j)
            acc[i][j] = (f32x4){0.f, 0.f, 0.f, 0.f};

    for (int it = 0; it < KITERS; ++it) {
        const int k0 = kbase + it * 32;
        __syncthreads();
        gl_lds16(Ah + (size_t)arow0 * KSTRIDE + k0 + kp, &AsH[aoff0]);
        gl_lds16(Ah + (size_t)arow1 * KSTRIDE + k0 + kp, &AsH[aoff1]);
        gl_lds16(Bh + (size_t)arow0 * KSTRIDE + k0 + kp, &BsH[aoff0]);
        if (SPLIT) {
            gl_lds16(Al + (size_t)arow0 * KSTRIDE + k0 + kp, &AsL[aoff0]);
            gl_lds16(Al + (size_t)arow1 * KSTRIDE + k0 + kp, &AsL[aoff1]);
            gl_lds16(Bl + (size_t)arow0 * KSTRIDE + k0 + kp, &BsL[aoff0]);
        }
        __syncthreads();

        short8 ah[4], al[4], bh[2], bl[2];
        #pragma unroll
        for (int i = 0; i < 4; ++i) {
            const int r = wm * 64 + i * 16 + fm;
            ah[i] = *(const short8*)&AsH[r * 32 + q8];
            if (SPLIT) al[i] = *(const short8*)&AsL[r * 32 + q8];
        }
        #pragma unroll
        for (int j = 0; j < 2; ++j) {
            const int r = wn * 32 + j * 16 + fm;
            bh[j] = *(const short8*)&BsH[r * 32 + q8];
            if (SPLIT) bl[j] = *(const short8*)&BsL[r * 32 + q8];
        }
        #pragma unroll
        for (int i = 0; i < 4; ++i)
            #pragma unroll
            for (int j = 0; j < 2; ++j) {
                acc[i][j] = __builtin_amdgcn_mfma_f32_16x16x32_bf16(ah[i], bh[j], acc[i][j], 0, 0, 0);
                if (SPLIT) {
                    acc[i][j] = __builtin_amdgcn_mfma_f32_16x16x32_bf16(ah[i], bl[j], acc[i][j], 0, 0, 0);
                    acc[i][j] = __builtin_amdgcn_mfma_f32_16x16x32_bf16(al[i], bh[j], acc[i][j], 0, 0, 0);
                }
            }
    }

    const int crow0 = (lane >> 4) * 4;
    const int ccol = lane & 15;
    #pragma unroll
    for (int i = 0; i < 4; ++i) {
        const int m = mt * 128 + wm * 64 + i * 16 + crow0;
        #pragma unroll
        for (int j = 0; j < 2; ++j) {
            const int n = nt * 64 + wn * 32 + j * 16 + ccol;
            #pragma unroll
            for (int r = 0; r < 4; ++r) {
                const float v = acc[i][j][r];
                const size_t rowb = (size_t)b * SQL + (m + r);
                if (MODE == 0) {
                    atomicAdd(&C0[rowb * SKL + n], v);
                } else {
                    if (n < DD)        C0[rowb * DD + n] = v;
                    else if (n < NOUT) C1[rowb * (DD * DD) + (n - DD)] = v;
                }
            }
        }
    }
}

// ---------------------------------------------------------------------------
// Kernel 3 (merged): blocks [0,4096): row softmax js -> bf16 P (hi only).
// blocks [4096,..): Vt = [v_mean | v_cov]^T, bf16 hi, [n][k], zero-padded.
// ---------------------------------------------------------------------------
__global__ __launch_bounds__(256) void phase2_kernel(
    const float* __restrict__ js, ushort_t* __restrict__ ph,
    const float* __restrict__ vmean, const float* __restrict__ vcov,
    ushort_t* __restrict__ vth)
{
    __shared__ float sm[32 * 33];
    const int tid = threadIdx.x;
    if (blockIdx.x < (unsigned)(NBATCH * SQL)) {
        const float* p = js + (size_t)blockIdx.x * SKL;
        float2 v = *(const float2*)(p + 2 * tid);
        float m = fmaxf(v.x, v.y);
        #pragma unroll
        for (int o = 32; o > 0; o >>= 1) m = fmaxf(m, __shfl_xor(m, o));
        const int wid = tid >> 6, ln = tid & 63;
        if (ln == 0) sm[wid] = m;
        __syncthreads();
        m = fmaxf(fmaxf(sm[0], sm[1]), fmaxf(sm[2], sm[3]));
        float e0 = __expf(v.x - m), e1 = __expf(v.y - m);
        float s = e0 + e1;
        #pragma unroll
        for (int o = 32; o > 0; o >>= 1) s += __shfl_xor(s, o);
        if (ln == 0) sm[4 + wid] = s;
        __syncthreads();
        s = sm[4] + sm[5] + sm[6] + sm[7];
        float rs = 1.0f / s;
        size_t o = (size_t)blockIdx.x * SKL + 2 * tid;
        ph[o]     = f2bf(e0 * rs);
        ph[o + 1] = f2bf(e1 * rs);
    } else {
        const int vb = blockIdx.x - NBATCH * SQL;
        const int b = vb / (34 * 16), rem = vb % (34 * 16);
        const int kt = rem / 34, nt = rem % 34;
        const int n0 = nt * 32, k0 = kt * 32;
        const int tx = tid & 31, ty = tid >> 5;
        for (int r = ty; r < 32; r += 8) {
            const int k = k0 + r, n = n0 + tx;
            float v;
            if (n0 == 0)          v = vmean[((size_t)b * SKL + k) * DD + n];
            else if (n0 >= NOUT)  v = 0.f;
            else                  v = vcov[((size_t)b * SKL + k) * (DD * DD) + (n - DD)];
            sm[tx * 33 + r] = v;
        }
        __syncthreads();
        for (int r = ty; r < 32; r += 8) {
            const int n = n0 + r, k = k0 + tx;
            vth[((size_t)b * NVT + n) * SKL + k] = f2bf(sm[r * 33 + tx]);
        }
    }
}

// ---------------------------------------------------------------------------
extern "C" void kernel_launch(void* const* d_in, const int* in_sizes, int n_in,
                              void* d_out, int out_size, void* d_ws, size_t ws_size,
                              hipStream_t stream)
{
    const float* q_mean = (const float*)d_in[0];
    const float* q_cov  = (const float*)d_in[1];
    const float* k_mean = (const float*)d_in[2];
    const float* k_cov  = (const float*)d_in[3];
    const float* v_mean = (const float*)d_in[4];
    const float* v_cov  = (const float*)d_in[5];

    float* out_mean = (float*)d_out;                        // [8,512,32]
    float* out_cov  = out_mean + (size_t)NBATCH * SQL * DD; // [8,512,32,32]

    char* w = (char*)d_ws;
    const size_t FQN = (size_t)NBATCH * SQL * KF;
    ushort_t* fq_h = (ushort_t*)w;
    ushort_t* fq_l = fq_h + FQN;
    ushort_t* fk_h = fq_l + FQN;
    ushort_t* fk_l = fk_h + FQN;
    float*    js   = (float*)(fk_l + FQN);                  // 8*512*512 fp32
    ushort_t* vt_h = fq_h;
    ushort_t* p_h  = fk_h;

    feat_kernel<<<2 * NSITE / 8, 256, 0, stream>>>(
        q_mean, q_cov, k_mean, k_cov, fq_h, fq_l, fk_h, fk_l);
    hipMemsetAsync(js, 0, (size_t)NBATCH * SQL * SKL * sizeof(float), stream);
    gemm_split<0><<<dim3(SKL / 64, 8, NBATCH), 256, 0, stream>>>(
        fq_h, fq_l, fk_h, fk_l, js, nullptr);
    phase2_kernel<<<NBATCH * SQL + VS_BLOCKS, 256, 0, stream>>>(
        js, p_h, v_mean, v_cov, vt_h);
    gemm_split<1><<<dim3(NVT / 64, SQL / 128, NBATCH), 256, 0, stream>>>(
        p_h, nullptr, vt_h, nullptr, out_mean, out_cov);
}